// Round 11
// baseline (578.207 us; speedup 1.0000x reference)
//
#include <hip/hip_runtime.h>
#include <hip/hip_bf16.h>

// ---------------------------------------------------------------------------
// EncoderLayer on MI355X (gfx950), round 16.
// Change vs R15 (attn only): BQ 128->256, 8 waves/block (512 thr), 512
// blocks. KV panel now staged 8x instead of 16x (halved KV L2/HBM reads);
// staging = 1 K + 1 V gl_lds per wave per tile (16/tile, unchanged);
// counted gates vmcnt(4)/(2)/(0); LDS 96KB (Kt32+Vt32+Pt32).
// GEMMs / QKV(V via LDS transpose) / LN / prep frozen at R15.
// NOTE (R15 post-mortem): top-5 WRITE_SIZE=135MB is eviction-attributed
// (bit-identical across R12-R15 incl. V-fix) — not store amplification.
// ---------------------------------------------------------------------------

#define DM    1024
#define DFF   4096
#define NH    16
#define HD    64
#define BATCH 4
#define SEQ   2048
#define TOK   (BATCH * SEQ)   // 8192

typedef __attribute__((ext_vector_type(8))) __bf16 bf16x8;
typedef __attribute__((ext_vector_type(4))) float f32x4;
typedef __attribute__((ext_vector_type(16))) float f32x16;
typedef __attribute__((ext_vector_type(4))) unsigned short u16x4;
typedef __attribute__((ext_vector_type(8))) unsigned short u16x8;

typedef const __attribute__((address_space(1))) unsigned int* gas1_t;
typedef __attribute__((address_space(3))) unsigned int* las3_t;

__device__ __forceinline__ void gl_lds16(const void* g, void* l) {
  // async global->LDS, 16B per lane; LDS dest = wave-uniform base + lane*16
  __builtin_amdgcn_global_load_lds((gas1_t)g, (las3_t)l, 16, 0, 0);
}

__device__ __forceinline__ unsigned short f2bu(float x) {
  return __builtin_bit_cast(unsigned short, __float2bfloat16(x));
}

// pack hi16(a),hi16(b) -> (b | a<<16): bf16 truncation of two floats, 1 instr
__device__ __forceinline__ unsigned pk_bf16_trunc(float hi, float lo) {
  return __builtin_amdgcn_perm(__builtin_bit_cast(unsigned, hi),
                               __builtin_bit_cast(unsigned, lo), 0x07060302u);
}

// ---------------------------------------------------------------------------
// cast fp32 -> bf16 (vectorized x4)
// ---------------------------------------------------------------------------
__global__ __launch_bounds__(256) void cast_bf16(
    const float* __restrict__ in, unsigned short* __restrict__ out, int n4) {
  int i = blockIdx.x * 256 + threadIdx.x;
  if (i >= n4) return;
  float4 v = ((const float4*)in)[i];
  u16x4 o = {f2bu(v.x), f2bu(v.y), f2bu(v.z), f2bu(v.w)};
  ((u16x4*)out)[i] = o;
}

// ---------------------------------------------------------------------------
// out[n][k] = bf16(in[k][n])   (LDS-tiled transpose, block (32,8))
// ---------------------------------------------------------------------------
__global__ __launch_bounds__(256) void transpose_cast(
    const float* __restrict__ in, unsigned short* __restrict__ out, int K, int N) {
  __shared__ float tile[32][33];
  int n0 = blockIdx.x * 32, k0 = blockIdx.y * 32;
  int tx = threadIdx.x, ty = threadIdx.y;
#pragma unroll
  for (int i = 0; i < 4; ++i)
    tile[ty + 8 * i][tx] = in[(size_t)(k0 + ty + 8 * i) * N + n0 + tx];
  __syncthreads();
#pragma unroll
  for (int i = 0; i < 4; ++i)
    out[(size_t)(n0 + ty + 8 * i) * K + k0 + tx] = f2bu(tile[tx][ty + 8 * i]);
}

// 4 square (1024x1024) weight transposes in one launch (z selects matrix)
__global__ __launch_bounds__(256) void transpose_cast4(
    const float* __restrict__ A0, const float* __restrict__ A1,
    const float* __restrict__ A2, const float* __restrict__ A3,
    unsigned short* __restrict__ O0, unsigned short* __restrict__ O1,
    unsigned short* __restrict__ O2, unsigned short* __restrict__ O3) {
  __shared__ float tile[32][33];
  const float* in; unsigned short* out;
  switch (blockIdx.z) {
    case 0: in = A0; out = O0; break;
    case 1: in = A1; out = O1; break;
    case 2: in = A2; out = O2; break;
    default: in = A3; out = O3; break;
  }
  int n0 = blockIdx.x * 32, k0 = blockIdx.y * 32;
  int tx = threadIdx.x, ty = threadIdx.y;
#pragma unroll
  for (int i = 0; i < 4; ++i)
    tile[ty + 8 * i][tx] = in[(size_t)(k0 + ty + 8 * i) * DM + n0 + tx];
  __syncthreads();
#pragma unroll
  for (int i = 0; i < 4; ++i)
    out[(size_t)(n0 + ty + 8 * i) * DM + k0 + tx] = f2bu(tile[tx][ty + 8 * i]);
}

// ---------------------------------------------------------------------------
// 256x256 GEMM mainloop, 8-phase / 2-K-tile iteration (R12, frozen).
// ---------------------------------------------------------------------------
__device__ __forceinline__ void mma8(const bf16x8 a0, const bf16x8 a1,
                                     const bf16x8 b, f32x16* c0, f32x16* c1) {
  *c0 = __builtin_amdgcn_mfma_f32_32x32x16_bf16(a0, b, *c0, 0, 0, 0);
  *c1 = __builtin_amdgcn_mfma_f32_32x32x16_bf16(a1, b, *c1, 0, 0, 0);
}

__device__ __forceinline__ void mainloop256(
    const unsigned short* __restrict__ A, int lda,
    const unsigned short* __restrict__ Bt, int ldb, int Kl,
    int m0, int n0, unsigned short* As, unsigned short* Bs,
    f32x16 acc[2][2][2]) {
  const int tid = threadIdx.x, lane = tid & 63, w = tid >> 6;
  const int l31 = lane & 31, khalf = lane >> 5;
  const int wr = w >> 2, wc = w & 3;
  const int rA0 = wr * 64 + l31, rA1 = rA0 + 32, rB = wc * 32 + l31;

  // stage source pointers: half h, instr i. granule g = (i*8+w)*64+lane;
  // row r = g>>3 (0..127), LDS chunk = g&7, source chunk = (g&7)^(r&7).
  const unsigned short* pa[2][2];
  const unsigned short* pb[2][2];
#pragma unroll
  for (int h = 0; h < 2; ++h)
#pragma unroll
    for (int i = 0; i < 2; ++i) {
      const int g = (i * 8 + w) * 64 + lane;
      const int r = g >> 3;
      const int cs = ((g & 7) ^ (r & 7)) * 8;
      pa[h][i] = A + (size_t)(m0 + h * 128 + r) * lda + cs;
      pb[h][i] = Bt + (size_t)(n0 + h * 128 + r) * ldb + cs;
    }
  const int wofsB = w * 1024;  // byte offset of this wave's 1KB DMA slice

  bf16x8 aF[2][4], b0[4], b1[4];

#define STA(BUF, H, I) \
  gl_lds16(pa[H][I], (char*)As + (BUF) * 32768 + (H) * 16384 + (I) * 8192 + wofsB)
#define STB(BUF, H, I) \
  gl_lds16(pb[H][I], (char*)Bs + (BUF) * 32768 + (H) * 16384 + (I) * 8192 + wofsB)
#define ADV_A(H) { pa[H][0] += 64; pa[H][1] += 64; }
#define ADV_B(H) { pb[H][0] += 64; pb[H][1] += 64; }

#define RD_A(BUFB, H)                                                         \
  { const char* Ah = (const char*)As + (BUFB) + (H) * 16384;                  \
    _Pragma("unroll") for (int ks = 0; ks < 4; ++ks) {                        \
      const int c = ks * 2 + khalf;                                           \
      aF[0][ks] = *(const bf16x8*)(Ah + rA0 * 128 + ((c ^ (rA0 & 7)) << 4));  \
      aF[1][ks] = *(const bf16x8*)(Ah + rA1 * 128 + ((c ^ (rA1 & 7)) << 4));  \
    } }
#define RD_B(DST, BUFB, H)                                                    \
  { const char* Bh = (const char*)Bs + (BUFB) + (H) * 16384;                  \
    _Pragma("unroll") for (int ks = 0; ks < 4; ++ks) {                        \
      const int c = ks * 2 + khalf;                                           \
      DST[ks] = *(const bf16x8*)(Bh + rB * 128 + ((c ^ (rB & 7)) << 4));      \
    } }

#define MMA4(QM, QN, BV)                                                      \
  { __builtin_amdgcn_s_setprio(1);                                           \
    _Pragma("unroll") for (int ks = 0; ks < 4; ++ks)                          \
      mma8(aF[0][ks], aF[1][ks], BV[ks], &acc[QM][QN][0], &acc[QM][QN][1]);   \
    __builtin_amdgcn_s_setprio(0); }

#define BAR asm volatile("s_barrier" ::: "memory")

// One iteration = K-tiles t (buf0) then t+1 (buf1), 8 phases.
// SL: late stages (ph2-7) on/off. G3/G7: gate strings at ph3/ph7 barrier#1.
#define ITER(SL, G3, G7)                                                      \
  /* ph0 (buf0, 0,0) */                                                       \
  RD_A(0, 0); RD_B(b0, 0, 0);                                                 \
  STA(1, 1, 0); STA(1, 1, 1); ADV_A(1);                                       \
  BAR; MMA4(0, 0, b0); BAR;                                                   \
  /* ph1 (buf0, 0,1) */                                                       \
  RD_B(b1, 0, 1);                                                             \
  STB(1, 0, 0); STB(1, 0, 1); ADV_B(0);                                       \
  BAR; MMA4(0, 1, b1); BAR;                                                   \
  /* ph2 (buf0, 1,1) */                                                       \
  RD_A(0, 1);                                                                 \
  if (SL) { STA(0, 0, 0); STA(0, 0, 1); ADV_A(0); }                           \
  BAR; MMA4(1, 1, b1); BAR;                                                   \
  /* ph3 (buf0, 1,0) — gate confirms buf1 */                                  \
  if (SL) { STB(0, 1, 0); STB(0, 1, 1); ADV_B(1); }                           \
  asm volatile(G3 ::: "memory");                                              \
  MMA4(1, 0, b0); BAR;                                                        \
  /* ph4 (buf1, 0,0) */                                                       \
  RD_A(32768, 0); RD_B(b0, 32768, 0);                                         \
  if (SL) { STA(0, 1, 0); STA(0, 1, 1); ADV_A(1); }                           \
  BAR; MMA4(0, 0, b0); BAR;                                                   \
  /* ph5 (buf1, 0,1) */                                                       \
  RD_B(b1, 32768, 1);                                                         \
  if (SL) { STB(0, 0, 0); STB(0, 0, 1); ADV_B(0); }                           \
  BAR; MMA4(0, 1, b1); BAR;                                                   \
  /* ph6 (buf1, 1,1) */                                                       \
  RD_A(32768, 1);                                                             \
  if (SL) { STA(1, 0, 0); STA(1, 0, 1); ADV_A(0); }                           \
  BAR; MMA4(1, 1, b1); BAR;                                                   \
  /* ph7 (buf1, 1,0) — gate confirms buf0 (next iter) */                      \
  if (SL) { STB(1, 1, 0); STB(1, 1, 1); ADV_B(1); }                           \
  asm volatile(G7 ::: "memory");                                              \
  MMA4(1, 0, b0); BAR;

  // prologue: tile0 full -> buf0; tile1.A0,B1 -> buf1 (= virtual ph6,ph7).
  // Gate vmcnt(4): retire tile0 (8 loads), keep tile1's 4 in flight.
  STA(0, 0, 0); STA(0, 0, 1); ADV_A(0);
  STB(0, 0, 0); STB(0, 0, 1); ADV_B(0);
  STB(0, 1, 0); STB(0, 1, 1); ADV_B(1);
  STA(0, 1, 0); STA(0, 1, 1); ADV_A(1);
  STA(1, 0, 0); STA(1, 0, 1); ADV_A(0);
  STB(1, 1, 0); STB(1, 1, 1); ADV_B(1);
  asm volatile("s_waitcnt vmcnt(4)\n\ts_barrier" ::: "memory");

  const int L = (Kl >> 6) >> 1;  // iterations of 2 K-tiles; L >= 2
  for (int i = 0; i < L - 1; ++i) {
    ITER(1, "s_waitcnt vmcnt(4)\n\ts_barrier", "s_waitcnt vmcnt(4)\n\ts_barrier");
  }
  // tail iter: ph0/ph1 still stage tile NT-1's A1,B0; no late stages;
  // ph3 gate drains everything (8 outstanding), ph7 plain barrier.
  ITER(0, "s_waitcnt vmcnt(0)\n\ts_barrier", "s_barrier");

#undef ITER
#undef BAR
#undef MMA4
#undef RD_B
#undef RD_A
#undef ADV_B
#undef ADV_A
#undef STB
#undef STA
}

// C/D layout (32x32): col = lane&31, row = (reg&3) + 8*(reg>>2) + 4*(lane>>5)
// wave quadrant (qm,qn), frag mi: rows m0+qm*128+wr*64+mi*32, cols n0+qn*128+wc*32

// XCD-aware block swizzle: blocks with equal (lin%8) land on one XCD; give
// each XCD a contiguous chunk. Requires gridDim.x*gridDim.y % 8 == 0.
__device__ __forceinline__ void xcd_swizzle(int& bx, int& by) {
  const int gx = gridDim.x, nxy = gx * gridDim.y;
  int lin = by * gx + bx;
  lin = (lin & 7) * (nxy >> 3) + (lin >> 3);
  bx = lin % gx;
  by = lin / gx;
}

// ---------------------------------------------------------------------------
// Generic C[M,N] = epi(A @ Bt^T + bias).  gridDim.z=2 -> split-K: block z
// computes K-slice [z*Kl, (z+1)*Kl) into C0/C1 (bias only in z=0).
// ---------------------------------------------------------------------------
__global__ __launch_bounds__(512, 2) void gemm256(
    const unsigned short* __restrict__ A, int lda,
    const unsigned short* __restrict__ Bt, int ldb, int Kl,
    const float* __restrict__ bias, void* __restrict__ C0,
    void* __restrict__ C1, int N, float alpha, int relu, int ofp32) {
  __shared__ unsigned short As[32768];
  __shared__ unsigned short Bs[32768];
  const int tid = threadIdx.x, lane = tid & 63, w = tid >> 6;
  const int l31 = lane & 31, khalf = lane >> 5;
  const int wr = w >> 2, wc = w & 3;
  int bx = blockIdx.x, by = blockIdx.y;
  xcd_swizzle(bx, by);
  const int m0 = by * 256, n0 = bx * 256;
  const int koff = blockIdx.z * Kl;
  void* Cout = blockIdx.z ? C1 : C0;
  const float* be = blockIdx.z ? nullptr : bias;

  f32x16 acc[2][2][2];
#pragma unroll
  for (int qm = 0; qm < 2; ++qm)
#pragma unroll
    for (int qn = 0; qn < 2; ++qn)
#pragma unroll
      for (int mi = 0; mi < 2; ++mi)
#pragma unroll
        for (int r = 0; r < 16; ++r) acc[qm][qn][mi][r] = 0.f;

  mainloop256(A + koff, lda, Bt + koff, ldb, Kl, m0, n0, As, Bs, acc);

#pragma unroll
  for (int qn = 0; qn < 2; ++qn) {
    const int col = n0 + qn * 128 + wc * 32 + l31;
    const float bvv = be ? be[col] : 0.f;
#pragma unroll
    for (int qm = 0; qm < 2; ++qm)
#pragma unroll
      for (int mi = 0; mi < 2; ++mi) {
#pragma unroll
        for (int g = 0; g < 4; ++g) {
          const int rbase = m0 + qm * 128 + wr * 64 + mi * 32 + g * 8 + khalf * 4;
#pragma unroll
          for (int r = 0; r < 4; ++r) {
            float val = alpha * (acc[qm][qn][mi][g * 4 + r] + bvv);
            if (relu) val = fmaxf(val, 0.f);
            size_t idx = (size_t)(rbase + r) * N + col;
            if (ofp32) ((float*)Cout)[idx] = val;
            else ((unsigned short*)Cout)[idx] = f2bu(val);
          }
        }
      }
  }
}

// ---------------------------------------------------------------------------
// Fused QKV gemm (256x256). N=3072: region 0: Q * QSCALE -> Qb; 1: K -> Kb;
// 2: V -> Vtg transposed per head [(b*16+h)*64+d][s] via 128KB LDS transpose
// (SH = merged As/Bs, dead after mainloop): Vtg writes become 512B runs.
// ---------------------------------------------------------------------------
#define QSCALE 0.18033688f  // (1/sqrt(64)) * log2(e): softmax runs in exp2 domain
#define VKEY(c) (((c) & 31) * 8)  // XOR row-swizzle key (bits 3-7): keeps
                                  // u16x4 writes (r%4) and u16x8 reads (r%8)
                                  // contiguous; spreads banks 8-way.

__global__ __launch_bounds__(512, 2) void gemm_qkv256(
    const unsigned short* __restrict__ A, const unsigned short* __restrict__ Bt,
    const float* __restrict__ bq, const float* __restrict__ bk,
    const float* __restrict__ bv,
    unsigned short* __restrict__ Qb, unsigned short* __restrict__ Kb,
    unsigned short* __restrict__ Vtg) {
  __shared__ unsigned short SH[65536];  // mainloop: As=SH, Bs=SH+32768;
                                        // V-epilogue: 256x256 bf16 tile
  const int tid = threadIdx.x, lane = tid & 63, w = tid >> 6;
  const int l31 = lane & 31, khalf = lane >> 5;
  const int wr = w >> 2, wc = w & 3;
  int bx = blockIdx.x, by = blockIdx.y;
  xcd_swizzle(bx, by);
  const int m0 = by * 256, n0 = bx * 256;

  f32x16 acc[2][2][2];
#pragma unroll
  for (int qm = 0; qm < 2; ++qm)
#pragma unroll
    for (int qn = 0; qn < 2; ++qn)
#pragma unroll
      for (int mi = 0; mi < 2; ++mi)
#pragma unroll
        for (int r = 0; r < 16; ++r) acc[qm][qn][mi][r] = 0.f;

  mainloop256(A, DM, Bt, DM, DM, m0, n0, SH, SH + 32768, acc);

  const int region = n0 >> 10;  // 0=Q 1=K 2=V (256-tiles never straddle)
  if (region < 2) {
    unsigned short* Out = region ? Kb : Qb;
    const float* bias = region ? bk : bq;
    const float alpha = region ? 1.0f : QSCALE;
#pragma unroll
    for (int qn = 0; qn < 2; ++qn) {
      const int col = (n0 & 1023) + qn * 128 + wc * 32 + l31;
      const float bvv = bias[col];
#pragma unroll
      for (int qm = 0; qm < 2; ++qm)
#pragma unroll
        for (int mi = 0; mi < 2; ++mi) {
#pragma unroll
          for (int g = 0; g < 4; ++g) {
            const int rbase = m0 + qm * 128 + wr * 64 + mi * 32 + g * 8 + khalf * 4;
#pragma unroll
            for (int r = 0; r < 4; ++r)
              Out[(size_t)(rbase + r) * DM + col] =
                  f2bu(alpha * (acc[qm][qn][mi][g * 4 + r] + bvv));
          }
        }
    }
  } else {
    // ---- V region: acc -> SH[dcol][srow] (swizzled), then coalesced writes
    __syncthreads();
#pragma unroll
    for (int qn = 0; qn < 2; ++qn) {
      const int cl = qn * 128 + wc * 32 + l31;          // tile-local d col
      const float bvv = bv[(n0 & 1023) + cl];
#pragma unroll
      for (int qm = 0; qm < 2; ++qm)
#pragma unroll
        for (int mi = 0; mi < 2; ++mi) {
#pragma unroll
          for (int g = 0; g < 4; ++g) {
            const int rl = qm * 128 + wr * 64 + mi * 32 + g * 8 + khalf * 4;
            u16x4 pk;
#pragma unroll
            for (int r = 0; r < 4; ++r)
              pk[r] = f2bu(acc[qm][qn][mi][g * 4 + r] + bvv);
            *(u16x4*)&SH[cl * 256 + (rl ^ VKEY(cl))] = pk;
          }
        }
    }
    __syncthreads();
    // read rows of SH, write Vtg in 512B runs (4 lanes = one 64B line/instr)
    const int b2 = m0 >> 11, s0g = m0 & 2047;
    const int jj = tid & 3;
#pragma unroll
    for (int pass = 0; pass < 2; ++pass) {
      const int dcol = (tid >> 2) + pass * 128;
      const int gcol = (n0 & 1023) + dcol;
      const int hh2 = gcol >> 6, dl2 = gcol & 63;
      unsigned short* dst =
          Vtg + ((size_t)((b2 * NH + hh2) * HD + dl2)) * SEQ + s0g;
#pragma unroll
      for (int c = 0; c < 8; ++c) {
        const int r0 = jj * 8 + c * 32;
        u16x8 v = *(const u16x8*)&SH[dcol * 256 + (r0 ^ VKEY(dcol))];
        *(u16x8*)(dst + r0) = v;
      }
    }
  }
}

// ---------------------------------------------------------------------------
// Flash attention, S^T formulation, BQ=256, 8 waves, NO-max exp2 softmax.
// R16: per (b,h), KV staged by 8 blocks (was 16) -> halved KV L2/HBM reads.
// 4-deep K/V LDS ring; staging 1 K + 1 V gl_lds per wave per tile; counted
// gates vmcnt(4)/(2)/(0) + single raw s_barrier per KV-tile. bh-locality
// XCD remap; setprio around MFMA clusters. LDS 96KB.
// ---------------------------------------------------------------------------
__global__ __launch_bounds__(512) void attn_kernel(
    const unsigned short* __restrict__ Q, const unsigned short* __restrict__ K,
    const unsigned short* __restrict__ Vtg, unsigned short* __restrict__ O) {
  __shared__ unsigned short Kt[4][64 * 64];   // [buf][kv][d] swizzled, 8KB x4
  __shared__ unsigned short Vt[4][64 * 64];   // [buf][d][kv] swizzled, 8KB x4
  __shared__ unsigned short Pt[8][32 * 64];   // per-wave [q][kv], 4KB x8

  const int tid = threadIdx.x, lane = tid & 63, w = tid >> 6;  // w: 0..7
  const int l15 = lane & 15, quad = lane >> 4;
  // bh-locality remap over 512 blocks: c=L&7 (XCD, round-robin dispatch),
  // m=(L>>3)&7, qb=L>>6 (8 q-blocks of 256 rows). bh = c*8+m pins all
  // q-blocks of a bh to one XCD. Bijective: 8*8*8 = 512.
  const int L = blockIdx.y * gridDim.x + blockIdx.x;  // 0..511
  const int bh = (L & 7) * 8 + ((L >> 3) & 7);
  const int q0 = (L >> 6) * 256;
  const int b = bh >> 4, hh = bh & 15;
  const size_t tokbase = (size_t)b * SEQ;

  bf16x8 qf[2][2];
#pragma unroll
  for (int qg = 0; qg < 2; ++qg)
#pragma unroll
    for (int kk = 0; kk < 2; ++kk)
      qf[qg][kk] = *(const bf16x8*)(Q +
          (tokbase + q0 + w * 32 + qg * 16 + l15) * DM + hh * HD + kk * 32 + quad * 8);

  float l_run[2] = {0.f, 0.f};
  f32x4 Oacc[2][4];
#pragma unroll
  for (int qg = 0; qg < 2; ++qg)
#pragma unroll
    for (int nt = 0; nt < 4; ++nt) Oacc[qg][nt] = {0.f, 0.f, 0.f, 0.f};

  char* ptw = (char*)&Pt[w][0];

  // staging: per wave 1 K-slice + 1 V-slice, 16B/lane. granule f = w*64+lane
  // (0..511); row = f>>3 (0..63), LDS chunk f&7, source chunk (f&7)^(row&7).
  const int f = w * 64 + lane;
  const int rowS = f >> 3;
  const int csrcS = ((f & 7) ^ (rowS & 7)) * 8;
  const unsigned short* kg = K + (tokbase + rowS) * DM + hh * HD + csrcS;
  const unsigned short* vg = Vtg + ((size_t)bh * HD + rowS) * SEQ + csrcS;

#define STAGE_KV(BUF)                                                         \
  { gl_lds16(kg, (char*)Kt + (BUF) * 8192 + w * 1024);                        \
    gl_lds16(vg, (char*)Vt + (BUF) * 8192 + w * 1024);                        \
    kg += 64 * DM;                                                            \
    vg += 64; }

  const int NT = SEQ / 64;  // 32
  // prologue: stage tiles 0 and 1 (4 loads/wave outstanding)
  STAGE_KV(0);
  STAGE_KV(1);

  for (int j = 0; j < NT; ++j) {
    const int buf = j & 3;
    if (j + 2 < NT) STAGE_KV((j + 2) & 3);
    // gate: retire tile j (per-wave count: 2 loads/tile), then barrier
    if (j < NT - 2)
      asm volatile("s_waitcnt vmcnt(4)\n\ts_barrier" ::: "memory");
    else if (j == NT - 2)
      asm volatile("s_waitcnt vmcnt(2)\n\ts_barrier" ::: "memory");
    else
      asm volatile("s_waitcnt vmcnt(0)\n\ts_barrier" ::: "memory");

    const char* ktb = (const char*)Kt + buf * 8192;
    const char* vtb = (const char*)Vt + buf * 8192;

    f32x4 S[2][4];
#pragma unroll
    for (int qg = 0; qg < 2; ++qg)
#pragma unroll
      for (int mt = 0; mt < 4; ++mt) S[qg][mt] = {0.f, 0.f, 0.f, 0.f};
    __builtin_amdgcn_s_setprio(1);
#pragma unroll
    for (int kk = 0; kk < 2; ++kk) {
#pragma unroll
      for (int mt = 0; mt < 4; ++mt) {
        bf16x8 aK = *(const bf16x8*)(ktb + (mt * 16 + l15) * 128 +
                                     (((kk * 4 + quad) ^ (l15 & 7)) * 16));
        S[0][mt] = __builtin_amdgcn_mfma_f32_16x16x32_bf16(aK, qf[0][kk], S[0][mt], 0, 0, 0);
        S[1][mt] = __builtin_amdgcn_mfma_f32_16x16x32_bf16(aK, qf[1][kk], S[1][mt], 0, 0, 0);
      }
    }
    __builtin_amdgcn_s_setprio(0);

#pragma unroll
    for (int qg = 0; qg < 2; ++qg) {
      float rs = 0.f;
#pragma unroll
      for (int mt = 0; mt < 4; ++mt) {
        float p0 = __builtin_amdgcn_exp2f(S[qg][mt][0]);
        float p1 = __builtin_amdgcn_exp2f(S[qg][mt][1]);
        float p2 = __builtin_amdgcn_exp2f(S[qg][mt][2]);
        float p3 = __builtin_amdgcn_exp2f(S[qg][mt][3]);
        rs += (p0 + p1) + (p2 + p3);
        uint2 pk = {pk_bf16_trunc(p1, p0), pk_bf16_trunc(p3, p2)};
        *(uint2*)(ptw + (qg * 16 + l15) * 128 +
                  (((mt * 2 + (quad >> 1)) ^ (l15 & 7)) * 16 + (quad & 1) * 8)) = pk;
      }
      l_run[qg] += rs;
    }

    __builtin_amdgcn_s_setprio(1);
#pragma unroll
    for (int kk = 0; kk < 2; ++kk) {
      bf16x8 aP[2];
#pragma unroll
      for (int qg = 0; qg < 2; ++qg)
        aP[qg] = *(const bf16x8*)(ptw + (qg * 16 + l15) * 128 +
                                  (((kk * 4 + quad) ^ (l15 & 7)) * 16));
#pragma unroll
      for (int nt = 0; nt < 4; ++nt) {
        bf16x8 bV = *(const bf16x8*)(vtb + (nt * 16 + l15) * 128 +
                                     (((kk * 4 + quad) ^ (l15 & 7)) * 16));
        Oacc[0][nt] = __builtin_amdgcn_mfma_f32_16x16x32_bf16(aP[0], bV, Oacc[0][nt], 0, 0, 0);
        Oacc[1][nt] = __builtin_amdgcn_mfma_f32_16x16x32_bf16(aP[1], bV, Oacc[1][nt], 0, 0, 0);
      }
    }
    __builtin_amdgcn_s_setprio(0);
  }
#undef STAGE_KV

  // row-sum broadcast via shfl (no LDS)
#pragma unroll
  for (int qg = 0; qg < 2; ++qg) {
    l_run[qg] += __shfl_xor(l_run[qg], 16);
    l_run[qg] += __shfl_xor(l_run[qg], 32);
  }
#pragma unroll
  for (int qg = 0; qg < 2; ++qg) {
    f32x4 li;
#pragma unroll
    for (int r = 0; r < 4; ++r) li[r] = 1.0f / __shfl(l_run[qg], quad * 4 + r);
#pragma unroll
    for (int nt = 0; nt < 4; ++nt)
#pragma unroll
      for (int r = 0; r < 4; ++r) {
        size_t tok = tokbase + q0 + w * 32 + qg * 16 + quad * 4 + r;
        O[tok * DM + hh * HD + nt * 16 + l15] = f2bu(Oacc[qg][nt][r] * li[r]);
      }
  }
}

// ---------------------------------------------------------------------------
// row-wise: s = base + d0 (+ d1); LN(s)*gamma+beta -> outf (fp32), outb (opt)
// ---------------------------------------------------------------------------
__global__ __launch_bounds__(256) void ln_res(
    const float* __restrict__ base, const float* __restrict__ d0,
    const float* __restrict__ d1,
    const float* __restrict__ gamma, const float* __restrict__ beta,
    float* __restrict__ outf, unsigned short* __restrict__ outb) {
  __shared__ float red[8];
  const int row = blockIdx.x, tid = threadIdx.x;
  const size_t rb = (size_t)row * DM;
  float4 xv = ((const float4*)(base + rb))[tid];
  float4 dv = ((const float4*)(d0 + rb))[tid];
  float s0 = xv.x + dv.x, s1 = xv.y + dv.y, s2 = xv.z + dv.z, s3 = xv.w + dv.w;
  if (d1) {
    float4 ev = ((const float4*)(d1 + rb))[tid];
    s0 += ev.x; s1 += ev.y; s2 += ev.z; s3 += ev.w;
  }
  float t = s0 + s1 + s2 + s3;
#pragma unroll
  for (int m = 1; m < 64; m <<= 1) t += __shfl_xor(t, m);
  if ((tid & 63) == 0) red[tid >> 6] = t;
  __syncthreads();
  float mu = (red[0] + red[1] + red[2] + red[3]) * (1.0f / DM);
  float dd0 = s0 - mu, dd1 = s1 - mu, dd2 = s2 - mu, dd3 = s3 - mu;
  float v = dd0 * dd0 + dd1 * dd1 + dd2 * dd2 + dd3 * dd3;
#pragma unroll
  for (int m = 1; m < 64; m <<= 1) v += __shfl_xor(v, m);
  if ((tid & 63) == 0) red[4 + (tid >> 6)] = v;
  __syncthreads();
  float var = (red[4] + red[5] + red[6] + red[7]) * (1.0f / DM);
  float rs = rsqrtf(var + 1e-5f);
  float4 gv = ((const float4*)gamma)[tid];
  float4 bv = ((const float4*)beta)[tid];
  float o0 = dd0 * rs * gv.x + bv.x;
  float o1 = dd1 * rs * gv.y + bv.y;
  float o2 = dd2 * rs * gv.z + bv.z;
  float o3 = dd3 * rs * gv.w + bv.w;
  float4 ov = {o0, o1, o2, o3};
  ((float4*)(outf + rb))[tid] = ov;
  if (outb) {
    u16x4 ob = {f2bu(o0), f2bu(o1), f2bu(o2), f2bu(o3)};
    ((u16x4*)(outb + rb))[tid] = ob;
  }
}

// ---------------------------------------------------------------------------
extern "C" void kernel_launch(void* const* d_in, const int* in_sizes, int n_in,
                              void* d_out, int out_size, void* d_ws, size_t ws_size,
                              hipStream_t stream) {
  const float* x   = (const float*)d_in[0];
  const float* Wq  = (const float*)d_in[1];  const float* bq  = (const float*)d_in[2];
  const float* Wk  = (const float*)d_in[3];  const float* bk  = (const float*)d_in[4];
  const float* Wv  = (const float*)d_in[5];  const float* bvv = (const float*)d_in[6];
  const float* Wo  = (const float*)d_in[7];  const float* bo  = (const float*)d_in[8];
  const float* W1  = (const float*)d_in[9];  const float* b1  = (const float*)d_in[10];
  const float* W2  = (const float*)d_in[11]; const float* b2  = (const float*)d_in[12];
  const float* g1  = (const float*)d_in[13]; const float* be1 = (const float*)d_in[14];
  const float* g2  = (const float*)d_in[15]; const float* be2 = (const float*)d_in[16];

  char* ws = (char*)d_ws;
  const size_t MB = 1ull << 20;
  unsigned short* xb    = (unsigned short*)(ws + 0 * MB);    // 16MB (later hb/ffo2 alias)
  unsigned short* wqkvT = (unsigned short*)(ws + 16 * MB);   // 6MB  [3072][1024]
  unsigned short* woT   = (unsigned short*)(ws + 22 * MB);   // 2MB
  unsigned short* w1T   = (unsigned short*)(ws + 24 * MB);   // 8MB
  unsigned short* w2T   = (unsigned short*)(ws + 32 * MB);   // 8MB
  unsigned short* Qb    = (unsigned short*)(ws + 40 * MB);   // 16MB
  unsigned short* Kb    = (unsigned short*)(ws + 56 * MB);   // 16MB
  unsigned short* Vtg   = (unsigned short*)(ws + 72 * MB);   // 32MB [(b,h,d)][s]
  unsigned short* aO    = (unsigned short*)(ws + 104 * MB);  // 16MB
  float*          prj   = (float*)(ws + 120 * MB);           // 32MB fp32
  float*          prj2  = (float*)(ws + 40 * MB);            // 32MB alias Qb/Kb (dead post-attn)
  float*          h     = (float*)(ws + 152 * MB);           // 32MB fp32
  unsigned short* hb    = (unsigned short*)(ws + 0 * MB);    // alias xb (dead)
  unsigned short* ffm   = (unsigned short*)(ws + 40 * MB);   // 64MB alias Qb..Vtg (post-LN1)
  float*          ffo   = (float*)(ws + 104 * MB);           // 32MB alias aO+prj
  float*          ffo2  = (float*)(ws + 0 * MB);             // 32MB alias xb/hb (dead by FF2)
  (void)ws_size; (void)in_sizes; (void)n_in; (void)out_size;

  // prep: cast x; weight transposes (B^T bf16); Wq/Wk/Wv stacked -> wqkvT
  cast_bf16<<<TOK * DM / 4 / 256, 256, 0, stream>>>(x, xb, TOK * DM / 4);
  transpose_cast4<<<dim3(DM / 32, DM / 32, 4), dim3(32, 8), 0, stream>>>(
      Wq, Wk, Wv, Wo, wqkvT, wqkvT + 1024 * 1024, wqkvT + 2048 * 1024, woT);
  transpose_cast<<<dim3(DFF / 32, DM / 32), dim3(32, 8), 0, stream>>>(W1, w1T, DM, DFF);
  transpose_cast<<<dim3(DM / 32, DFF / 32), dim3(32, 8), 0, stream>>>(W2, w2T, DFF, DM);

  // fused QKV projection (Q scaled for exp2-domain softmax; V transposed)
  gemm_qkv256<<<dim3(3 * DM / 256, TOK / 256), 512, 0, stream>>>(
      xb, wqkvT, bq, bk, bvv, Qb, Kb, Vtg);

  // attention (BQ=256, 8 waves)
  attn_kernel<<<dim3(SEQ / 256, BATCH * NH), 512, 0, stream>>>(Qb, Kb, Vtg, aO);

  // output projection, split-K x2 (fills 256 blocks; fp32 partials)
  gemm256<<<dim3(DM / 256, TOK / 256, 2), 512, 0, stream>>>(
      aO, DM, woT, DM, DM / 2, bo, prj, prj2, DM, 1.0f, 0, 1);
  // LN1: h = LN(x + prj + prj2) -> fp32 h + bf16 hb
  ln_res<<<TOK, 256, 0, stream>>>(x, prj, prj2, g1, be1, h, hb);

  // FF1: relu(hb @ W1 + b1) -> bf16 ffm
  gemm256<<<dim3(DFF / 256, TOK / 256, 1), 512, 0, stream>>>(
      hb, DM, w1T, DM, DM, b1, ffm, nullptr, DFF, 1.0f, 1, 0);
  // FF2 split-K (z=0: k[0,2048) + bias -> ffo; z=1: k[2048,4096) -> ffo2)
  gemm256<<<dim3(DM / 256, TOK / 256, 2), 512, 0, stream>>>(
      ffm, DFF, w2T, DFF, DFF / 2, b2, ffo, ffo2, DM, 1.0f, 0, 1);

  // LN2 -> d_out (fp32): LN(h + ffo + ffo2)
  ln_res<<<TOK, 256, 0, stream>>>(h, ffo, ffo2, g2, be2, (float*)d_out, nullptr);
}

// Round 13
// 562.789 us; speedup vs baseline: 1.0274x; 1.0274x over previous
//
#include <hip/hip_runtime.h>
#include <hip/hip_bf16.h>

// ---------------------------------------------------------------------------
// EncoderLayer on MI355X (gfx950), round 18 (= R17 resubmit; R17 bench was an
// infra failure — container acquisition, kernel never executed).
// = R15 (best, 573.7us) + bf16 intermediate partials:
//   Wo and FF2 split-K partials (prj/prj2, ffo/ffo2) stored as bf16 instead
//   of fp32 (-128MB HBM traffic across 2 GEMM epilogues + 2 LN reads);
//   ln_res reads bf16 deltas. Attn = R15 (BQ=128). GEMMs / QKV / prep frozen.
// ---------------------------------------------------------------------------

#define DM    1024
#define DFF   4096
#define NH    16
#define HD    64
#define BATCH 4
#define SEQ   2048
#define TOK   (BATCH * SEQ)   // 8192

typedef __attribute__((ext_vector_type(8))) __bf16 bf16x8;
typedef __attribute__((ext_vector_type(4))) float f32x4;
typedef __attribute__((ext_vector_type(16))) float f32x16;
typedef __attribute__((ext_vector_type(4))) unsigned short u16x4;
typedef __attribute__((ext_vector_type(8))) unsigned short u16x8;

typedef const __attribute__((address_space(1))) unsigned int* gas1_t;
typedef __attribute__((address_space(3))) unsigned int* las3_t;

__device__ __forceinline__ void gl_lds16(const void* g, void* l) {
  // async global->LDS, 16B per lane; LDS dest = wave-uniform base + lane*16
  __builtin_amdgcn_global_load_lds((gas1_t)g, (las3_t)l, 16, 0, 0);
}

__device__ __forceinline__ unsigned short f2bu(float x) {
  return __builtin_bit_cast(unsigned short, __float2bfloat16(x));
}

__device__ __forceinline__ float bu2f(unsigned short u) {
  return __builtin_bit_cast(float, ((unsigned)u) << 16);
}

// pack hi16(a),hi16(b) -> (b | a<<16): bf16 truncation of two floats, 1 instr
__device__ __forceinline__ unsigned pk_bf16_trunc(float hi, float lo) {
  return __builtin_amdgcn_perm(__builtin_bit_cast(unsigned, hi),
                               __builtin_bit_cast(unsigned, lo), 0x07060302u);
}

// ---------------------------------------------------------------------------
// cast fp32 -> bf16 (vectorized x4)
// ---------------------------------------------------------------------------
__global__ __launch_bounds__(256) void cast_bf16(
    const float* __restrict__ in, unsigned short* __restrict__ out, int n4) {
  int i = blockIdx.x * 256 + threadIdx.x;
  if (i >= n4) return;
  float4 v = ((const float4*)in)[i];
  u16x4 o = {f2bu(v.x), f2bu(v.y), f2bu(v.z), f2bu(v.w)};
  ((u16x4*)out)[i] = o;
}

// ---------------------------------------------------------------------------
// out[n][k] = bf16(in[k][n])   (LDS-tiled transpose, block (32,8))
// ---------------------------------------------------------------------------
__global__ __launch_bounds__(256) void transpose_cast(
    const float* __restrict__ in, unsigned short* __restrict__ out, int K, int N) {
  __shared__ float tile[32][33];
  int n0 = blockIdx.x * 32, k0 = blockIdx.y * 32;
  int tx = threadIdx.x, ty = threadIdx.y;
#pragma unroll
  for (int i = 0; i < 4; ++i)
    tile[ty + 8 * i][tx] = in[(size_t)(k0 + ty + 8 * i) * N + n0 + tx];
  __syncthreads();
#pragma unroll
  for (int i = 0; i < 4; ++i)
    out[(size_t)(n0 + ty + 8 * i) * K + k0 + tx] = f2bu(tile[tx][ty + 8 * i]);
}

// 4 square (1024x1024) weight transposes in one launch (z selects matrix)
__global__ __launch_bounds__(256) void transpose_cast4(
    const float* __restrict__ A0, const float* __restrict__ A1,
    const float* __restrict__ A2, const float* __restrict__ A3,
    unsigned short* __restrict__ O0, unsigned short* __restrict__ O1,
    unsigned short* __restrict__ O2, unsigned short* __restrict__ O3) {
  __shared__ float tile[32][33];
  const float* in; unsigned short* out;
  switch (blockIdx.z) {
    case 0: in = A0; out = O0; break;
    case 1: in = A1; out = O1; break;
    case 2: in = A2; out = O2; break;
    default: in = A3; out = O3; break;
  }
  int n0 = blockIdx.x * 32, k0 = blockIdx.y * 32;
  int tx = threadIdx.x, ty = threadIdx.y;
#pragma unroll
  for (int i = 0; i < 4; ++i)
    tile[ty + 8 * i][tx] = in[(size_t)(k0 + ty + 8 * i) * DM + n0 + tx];
  __syncthreads();
#pragma unroll
  for (int i = 0; i < 4; ++i)
    out[(size_t)(n0 + ty + 8 * i) * DM + k0 + tx] = f2bu(tile[tx][ty + 8 * i]);
}

// ---------------------------------------------------------------------------
// 256x256 GEMM mainloop, 8-phase / 2-K-tile iteration (R12, frozen).
// ---------------------------------------------------------------------------
__device__ __forceinline__ void mma8(const bf16x8 a0, const bf16x8 a1,
                                     const bf16x8 b, f32x16* c0, f32x16* c1) {
  *c0 = __builtin_amdgcn_mfma_f32_32x32x16_bf16(a0, b, *c0, 0, 0, 0);
  *c1 = __builtin_amdgcn_mfma_f32_32x32x16_bf16(a1, b, *c1, 0, 0, 0);
}

__device__ __forceinline__ void mainloop256(
    const unsigned short* __restrict__ A, int lda,
    const unsigned short* __restrict__ Bt, int ldb, int Kl,
    int m0, int n0, unsigned short* As, unsigned short* Bs,
    f32x16 acc[2][2][2]) {
  const int tid = threadIdx.x, lane = tid & 63, w = tid >> 6;
  const int l31 = lane & 31, khalf = lane >> 5;
  const int wr = w >> 2, wc = w & 3;
  const int rA0 = wr * 64 + l31, rA1 = rA0 + 32, rB = wc * 32 + l31;

  // stage source pointers: half h, instr i. granule g = (i*8+w)*64+lane;
  // row r = g>>3 (0..127), LDS chunk = g&7, source chunk = (g&7)^(r&7).
  const unsigned short* pa[2][2];
  const unsigned short* pb[2][2];
#pragma unroll
  for (int h = 0; h < 2; ++h)
#pragma unroll
    for (int i = 0; i < 2; ++i) {
      const int g = (i * 8 + w) * 64 + lane;
      const int r = g >> 3;
      const int cs = ((g & 7) ^ (r & 7)) * 8;
      pa[h][i] = A + (size_t)(m0 + h * 128 + r) * lda + cs;
      pb[h][i] = Bt + (size_t)(n0 + h * 128 + r) * ldb + cs;
    }
  const int wofsB = w * 1024;  // byte offset of this wave's 1KB DMA slice

  bf16x8 aF[2][4], b0[4], b1[4];

#define STA(BUF, H, I) \
  gl_lds16(pa[H][I], (char*)As + (BUF) * 32768 + (H) * 16384 + (I) * 8192 + wofsB)
#define STB(BUF, H, I) \
  gl_lds16(pb[H][I], (char*)Bs + (BUF) * 32768 + (H) * 16384 + (I) * 8192 + wofsB)
#define ADV_A(H) { pa[H][0] += 64; pa[H][1] += 64; }
#define ADV_B(H) { pb[H][0] += 64; pb[H][1] += 64; }

#define RD_A(BUFB, H)                                                         \
  { const char* Ah = (const char*)As + (BUFB) + (H) * 16384;                  \
    _Pragma("unroll") for (int ks = 0; ks < 4; ++ks) {                        \
      const int c = ks * 2 + khalf;                                           \
      aF[0][ks] = *(const bf16x8*)(Ah + rA0 * 128 + ((c ^ (rA0 & 7)) << 4));  \
      aF[1][ks] = *(const bf16x8*)(Ah + rA1 * 128 + ((c ^ (rA1 & 7)) << 4));  \
    } }
#define RD_B(DST, BUFB, H)                                                    \
  { const char* Bh = (const char*)Bs + (BUFB) + (H) * 16384;                  \
    _Pragma("unroll") for (int ks = 0; ks < 4; ++ks) {                        \
      const int c = ks * 2 + khalf;                                           \
      DST[ks] = *(const bf16x8*)(Bh + rB * 128 + ((c ^ (rB & 7)) << 4));      \
    } }

#define MMA4(QM, QN, BV)                                                      \
  { __builtin_amdgcn_s_setprio(1);                                           \
    _Pragma("unroll") for (int ks = 0; ks < 4; ++ks)                          \
      mma8(aF[0][ks], aF[1][ks], BV[ks], &acc[QM][QN][0], &acc[QM][QN][1]);   \
    __builtin_amdgcn_s_setprio(0); }

#define BAR asm volatile("s_barrier" ::: "memory")

// One iteration = K-tiles t (buf0) then t+1 (buf1), 8 phases.
// SL: late stages (ph2-7) on/off. G3/G7: gate strings at ph3/ph7 barrier#1.
#define ITER(SL, G3, G7)                                                      \
  /* ph0 (buf0, 0,0) */                                                       \
  RD_A(0, 0); RD_B(b0, 0, 0);                                                 \
  STA(1, 1, 0); STA(1, 1, 1); ADV_A(1);                                       \
  BAR; MMA4(0, 0, b0); BAR;                                                   \
  /* ph1 (buf0, 0,1) */                                                       \
  RD_B(b1, 0, 1);                                                             \
  STB(1, 0, 0); STB(1, 0, 1); ADV_B(0);                                       \
  BAR; MMA4(0, 1, b1); BAR;                                                   \
  /* ph2 (buf0, 1,1) */                                                       \
  RD_A(0, 1);                                                                 \
  if (SL) { STA(0, 0, 0); STA(0, 0, 1); ADV_A(0); }                           \
  BAR; MMA4(1, 1, b1); BAR;                                                   \
  /* ph3 (buf0, 1,0) — gate confirms buf1 */                                  \
  if (SL) { STB(0, 1, 0); STB(0, 1, 1); ADV_B(1); }                           \
  asm volatile(G3 ::: "memory");                                              \
  MMA4(1, 0, b0); BAR;                                                        \
  /* ph4 (buf1, 0,0) */                                                       \
  RD_A(32768, 0); RD_B(b0, 32768, 0);                                         \
  if (SL) { STA(0, 1, 0); STA(0, 1, 1); ADV_A(1); }                           \
  BAR; MMA4(0, 0, b0); BAR;                                                   \
  /* ph5 (buf1, 0,1) */                                                       \
  RD_B(b1, 32768, 1);                                                         \
  if (SL) { STB(0, 0, 0); STB(0, 0, 1); ADV_B(0); }                           \
  BAR; MMA4(0, 1, b1); BAR;                                                   \
  /* ph6 (buf1, 1,1) */                                                       \
  RD_A(32768, 1);                                                             \
  if (SL) { STA(1, 0, 0); STA(1, 0, 1); ADV_A(0); }                           \
  BAR; MMA4(1, 1, b1); BAR;                                                   \
  /* ph7 (buf1, 1,0) — gate confirms buf0 (next iter) */                      \
  if (SL) { STB(1, 1, 0); STB(1, 1, 1); ADV_B(1); }                           \
  asm volatile(G7 ::: "memory");                                              \
  MMA4(1, 0, b0); BAR;

  // prologue: tile0 full -> buf0; tile1.A0,B1 -> buf1 (= virtual ph6,ph7).
  // Gate vmcnt(4): retire tile0 (8 loads), keep tile1's 4 in flight.
  STA(0, 0, 0); STA(0, 0, 1); ADV_A(0);
  STB(0, 0, 0); STB(0, 0, 1); ADV_B(0);
  STB(0, 1, 0); STB(0, 1, 1); ADV_B(1);
  STA(0, 1, 0); STA(0, 1, 1); ADV_A(1);
  STA(1, 0, 0); STA(1, 0, 1); ADV_A(0);
  STB(1, 1, 0); STB(1, 1, 1); ADV_B(1);
  asm volatile("s_waitcnt vmcnt(4)\n\ts_barrier" ::: "memory");

  const int L = (Kl >> 6) >> 1;  // iterations of 2 K-tiles; L >= 2
  for (int i = 0; i < L - 1; ++i) {
    ITER(1, "s_waitcnt vmcnt(4)\n\ts_barrier", "s_waitcnt vmcnt(4)\n\ts_barrier");
  }
  // tail iter: ph0/ph1 still stage tile NT-1's A1,B0; no late stages;
  // ph3 gate drains everything (8 outstanding), ph7 plain barrier.
  ITER(0, "s_waitcnt vmcnt(0)\n\ts_barrier", "s_barrier");

#undef ITER
#undef BAR
#undef MMA4
#undef RD_B
#undef RD_A
#undef ADV_B
#undef ADV_A
#undef STB
#undef STA
}

// C/D layout (32x32): col = lane&31, row = (reg&3) + 8*(reg>>2) + 4*(lane>>5)
// wave quadrant (qm,qn), frag mi: rows m0+qm*128+wr*64+mi*32, cols n0+qn*128+wc*32

// XCD-aware block swizzle: blocks with equal (lin%8) land on one XCD; give
// each XCD a contiguous chunk. Requires gridDim.x*gridDim.y % 8 == 0.
__device__ __forceinline__ void xcd_swizzle(int& bx, int& by) {
  const int gx = gridDim.x, nxy = gx * gridDim.y;
  int lin = by * gx + bx;
  lin = (lin & 7) * (nxy >> 3) + (lin >> 3);
  bx = lin % gx;
  by = lin / gx;
}

// ---------------------------------------------------------------------------
// Generic C[M,N] = epi(A @ Bt^T + bias).  gridDim.z=2 -> split-K: block z
// computes K-slice [z*Kl, (z+1)*Kl) into C0/C1 (bias only in z=0).
// ---------------------------------------------------------------------------
__global__ __launch_bounds__(512, 2) void gemm256(
    const unsigned short* __restrict__ A, int lda,
    const unsigned short* __restrict__ Bt, int ldb, int Kl,
    const float* __restrict__ bias, void* __restrict__ C0,
    void* __restrict__ C1, int N, float alpha, int relu, int ofp32) {
  __shared__ unsigned short As[32768];
  __shared__ unsigned short Bs[32768];
  const int tid = threadIdx.x, lane = tid & 63, w = tid >> 6;
  const int l31 = lane & 31, khalf = lane >> 5;
  const int wr = w >> 2, wc = w & 3;
  int bx = blockIdx.x, by = blockIdx.y;
  xcd_swizzle(bx, by);
  const int m0 = by * 256, n0 = bx * 256;
  const int koff = blockIdx.z * Kl;
  void* Cout = blockIdx.z ? C1 : C0;
  const float* be = blockIdx.z ? nullptr : bias;

  f32x16 acc[2][2][2];
#pragma unroll
  for (int qm = 0; qm < 2; ++qm)
#pragma unroll
    for (int qn = 0; qn < 2; ++qn)
#pragma unroll
      for (int mi = 0; mi < 2; ++mi)
#pragma unroll
        for (int r = 0; r < 16; ++r) acc[qm][qn][mi][r] = 0.f;

  mainloop256(A + koff, lda, Bt + koff, ldb, Kl, m0, n0, As, Bs, acc);

#pragma unroll
  for (int qn = 0; qn < 2; ++qn) {
    const int col = n0 + qn * 128 + wc * 32 + l31;
    const float bvv = be ? be[col] : 0.f;
#pragma unroll
    for (int qm = 0; qm < 2; ++qm)
#pragma unroll
      for (int mi = 0; mi < 2; ++mi) {
#pragma unroll
        for (int g = 0; g < 4; ++g) {
          const int rbase = m0 + qm * 128 + wr * 64 + mi * 32 + g * 8 + khalf * 4;
#pragma unroll
          for (int r = 0; r < 4; ++r) {
            float val = alpha * (acc[qm][qn][mi][g * 4 + r] + bvv);
            if (relu) val = fmaxf(val, 0.f);
            size_t idx = (size_t)(rbase + r) * N + col;
            if (ofp32) ((float*)Cout)[idx] = val;
            else ((unsigned short*)Cout)[idx] = f2bu(val);
          }
        }
      }
  }
}

// ---------------------------------------------------------------------------
// Fused QKV gemm (256x256). N=3072: region 0: Q * QSCALE -> Qb; 1: K -> Kb;
// 2: V -> Vtg transposed per head [(b*16+h)*64+d][s] via 128KB LDS transpose
// (SH = merged As/Bs, dead after mainloop): Vtg writes become 512B runs.
// ---------------------------------------------------------------------------
#define QSCALE 0.18033688f  // (1/sqrt(64)) * log2(e): softmax runs in exp2 domain
#define VKEY(c) (((c) & 31) * 8)  // XOR row-swizzle key (bits 3-7): keeps
                                  // u16x4 writes (r%4) and u16x8 reads (r%8)
                                  // contiguous; spreads banks 8-way.

__global__ __launch_bounds__(512, 2) void gemm_qkv256(
    const unsigned short* __restrict__ A, const unsigned short* __restrict__ Bt,
    const float* __restrict__ bq, const float* __restrict__ bk,
    const float* __restrict__ bv,
    unsigned short* __restrict__ Qb, unsigned short* __restrict__ Kb,
    unsigned short* __restrict__ Vtg) {
  __shared__ unsigned short SH[65536];  // mainloop: As=SH, Bs=SH+32768;
                                        // V-epilogue: 256x256 bf16 tile
  const int tid = threadIdx.x, lane = tid & 63, w = tid >> 6;
  const int l31 = lane & 31, khalf = lane >> 5;
  const int wr = w >> 2, wc = w & 3;
  int bx = blockIdx.x, by = blockIdx.y;
  xcd_swizzle(bx, by);
  const int m0 = by * 256, n0 = bx * 256;

  f32x16 acc[2][2][2];
#pragma unroll
  for (int qm = 0; qm < 2; ++qm)
#pragma unroll
    for (int qn = 0; qn < 2; ++qn)
#pragma unroll
      for (int mi = 0; mi < 2; ++mi)
#pragma unroll
        for (int r = 0; r < 16; ++r) acc[qm][qn][mi][r] = 0.f;

  mainloop256(A, DM, Bt, DM, DM, m0, n0, SH, SH + 32768, acc);

  const int region = n0 >> 10;  // 0=Q 1=K 2=V (256-tiles never straddle)
  if (region < 2) {
    unsigned short* Out = region ? Kb : Qb;
    const float* bias = region ? bk : bq;
    const float alpha = region ? 1.0f : QSCALE;
#pragma unroll
    for (int qn = 0; qn < 2; ++qn) {
      const int col = (n0 & 1023) + qn * 128 + wc * 32 + l31;
      const float bvv = bias[col];
#pragma unroll
      for (int qm = 0; qm < 2; ++qm)
#pragma unroll
        for (int mi = 0; mi < 2; ++mi) {
#pragma unroll
          for (int g = 0; g < 4; ++g) {
            const int rbase = m0 + qm * 128 + wr * 64 + mi * 32 + g * 8 + khalf * 4;
#pragma unroll
            for (int r = 0; r < 4; ++r)
              Out[(size_t)(rbase + r) * DM + col] =
                  f2bu(alpha * (acc[qm][qn][mi][g * 4 + r] + bvv));
          }
        }
    }
  } else {
    // ---- V region: acc -> SH[dcol][srow] (swizzled), then coalesced writes
    __syncthreads();
#pragma unroll
    for (int qn = 0; qn < 2; ++qn) {
      const int cl = qn * 128 + wc * 32 + l31;          // tile-local d col
      const float bvv = bv[(n0 & 1023) + cl];
#pragma unroll
      for (int qm = 0; qm < 2; ++qm)
#pragma unroll
        for (int mi = 0; mi < 2; ++mi) {
#pragma unroll
          for (int g = 0; g < 4; ++g) {
            const int rl = qm * 128 + wr * 64 + mi * 32 + g * 8 + khalf * 4;
            u16x4 pk;
#pragma unroll
            for (int r = 0; r < 4; ++r)
              pk[r] = f2bu(acc[qm][qn][mi][g * 4 + r] + bvv);
            *(u16x4*)&SH[cl * 256 + (rl ^ VKEY(cl))] = pk;
          }
        }
    }
    __syncthreads();
    // read rows of SH, write Vtg in 512B runs (4 lanes = one 64B line/instr)
    const int b2 = m0 >> 11, s0g = m0 & 2047;
    const int jj = tid & 3;
#pragma unroll
    for (int pass = 0; pass < 2; ++pass) {
      const int dcol = (tid >> 2) + pass * 128;
      const int gcol = (n0 & 1023) + dcol;
      const int hh2 = gcol >> 6, dl2 = gcol & 63;
      unsigned short* dst =
          Vtg + ((size_t)((b2 * NH + hh2) * HD + dl2)) * SEQ + s0g;
#pragma unroll
      for (int c = 0; c < 8; ++c) {
        const int r0 = jj * 8 + c * 32;
        u16x8 v = *(const u16x8*)&SH[dcol * 256 + (r0 ^ VKEY(dcol))];
        *(u16x8*)(dst + r0) = v;
      }
    }
  }
}

// ---------------------------------------------------------------------------
// Flash attention, S^T formulation, BQ=128, NO-max exp2 softmax (R15).
// bh-locality XCD remap + setprio around MFMA clusters.
// 4-deep K/V LDS ring, counted vmcnt(8) + single raw s_barrier per KV-tile.
// ---------------------------------------------------------------------------
__global__ __launch_bounds__(256) void attn_kernel(
    const unsigned short* __restrict__ Q, const unsigned short* __restrict__ K,
    const unsigned short* __restrict__ Vtg, unsigned short* __restrict__ O) {
  __shared__ unsigned short Kt[4][64 * 64];   // [buf][kv][d] swizzled, 8KB x4
  __shared__ unsigned short Vt[4][64 * 64];   // [buf][d][kv] swizzled, 8KB x4
  __shared__ unsigned short Pt[4][32 * 64];   // per-wave [q][kv], 4KB x4

  const int tid = threadIdx.x, lane = tid & 63, w = tid >> 6;
  const int l15 = lane & 15, quad = lane >> 4;
  // bh-locality remap: launch-linear L -> XCD c = L&7 (round-robin dispatch);
  // bh = c*8 + ((L>>3)&7) pins all q-blocks of bh to XCD c; qb = L>>6.
  const int L = blockIdx.y * gridDim.x + blockIdx.x;  // 0..1023
  const int bh = (L & 7) * 8 + ((L >> 3) & 7);
  const int q0 = (L >> 6) * 128;
  const int b = bh >> 4, hh = bh & 15;
  const size_t tokbase = (size_t)b * SEQ;

  bf16x8 qf[2][2];
#pragma unroll
  for (int qg = 0; qg < 2; ++qg)
#pragma unroll
    for (int kk = 0; kk < 2; ++kk)
      qf[qg][kk] = *(const bf16x8*)(Q +
          (tokbase + q0 + w * 32 + qg * 16 + l15) * DM + hh * HD + kk * 32 + quad * 8);

  float l_run[2] = {0.f, 0.f};
  f32x4 Oacc[2][4];
#pragma unroll
  for (int qg = 0; qg < 2; ++qg)
#pragma unroll
    for (int nt = 0; nt < 4; ++nt) Oacc[qg][nt] = {0.f, 0.f, 0.f, 0.f};

  char* ptw = (char*)&Pt[w][0];

  // staging: per wave 2 K-slices + 2 V-slices (i=0,1), 16B/lane each.
  int rowS[2], csrcS[2];
#pragma unroll
  for (int i = 0; i < 2; ++i) {
    int f = (i * 4 + w) * 64 + lane;
    rowS[i] = f >> 3;
    csrcS[i] = ((f & 7) ^ (rowS[i] & 7)) * 8;
  }
  const unsigned short* kg[2];
  const unsigned short* vg[2];
#pragma unroll
  for (int i = 0; i < 2; ++i) {
    kg[i] = K + (tokbase + rowS[i]) * DM + hh * HD + csrcS[i];
    vg[i] = Vtg + ((size_t)bh * HD + rowS[i]) * SEQ + csrcS[i];
  }

#define STAGE_KV(BUF)                                                         \
  { _Pragma("unroll") for (int i = 0; i < 2; ++i) {                           \
      gl_lds16(kg[i], (char*)Kt + (BUF) * 8192 + (i * 4 + w) * 1024);         \
      gl_lds16(vg[i], (char*)Vt + (BUF) * 8192 + (i * 4 + w) * 1024);         \
      kg[i] += 64 * DM;                                                       \
      vg[i] += 64;                                                            \
    } }

  const int NT = SEQ / 64;  // 32
  // prologue: stage tiles 0 and 1
  STAGE_KV(0);
  STAGE_KV(1);

  for (int j = 0; j < NT; ++j) {
    const int buf = j & 3;
    if (j + 2 < NT) STAGE_KV((j + 2) & 3);
    // gate: retire tile j (per-wave count), then block-wide barrier
    if (j < NT - 2)
      asm volatile("s_waitcnt vmcnt(8)\n\ts_barrier" ::: "memory");
    else if (j == NT - 2)
      asm volatile("s_waitcnt vmcnt(4)\n\ts_barrier" ::: "memory");
    else
      asm volatile("s_waitcnt vmcnt(0)\n\ts_barrier" ::: "memory");

    const char* ktb = (const char*)Kt + buf * 8192;
    const char* vtb = (const char*)Vt + buf * 8192;

    f32x4 S[2][4];
#pragma unroll
    for (int qg = 0; qg < 2; ++qg)
#pragma unroll
      for (int mt = 0; mt < 4; ++mt) S[qg][mt] = {0.f, 0.f, 0.f, 0.f};
    __builtin_amdgcn_s_setprio(1);
#pragma unroll
    for (int kk = 0; kk < 2; ++kk) {
#pragma unroll
      for (int mt = 0; mt < 4; ++mt) {
        bf16x8 aK = *(const bf16x8*)(ktb + (mt * 16 + l15) * 128 +
                                     (((kk * 4 + quad) ^ (l15 & 7)) * 16));
        S[0][mt] = __builtin_amdgcn_mfma_f32_16x16x32_bf16(aK, qf[0][kk], S[0][mt], 0, 0, 0);
        S[1][mt] = __builtin_amdgcn_mfma_f32_16x16x32_bf16(aK, qf[1][kk], S[1][mt], 0, 0, 0);
      }
    }
    __builtin_amdgcn_s_setprio(0);

#pragma unroll
    for (int qg = 0; qg < 2; ++qg) {
      float rs = 0.f;
#pragma unroll
      for (int mt = 0; mt < 4; ++mt) {
        float p0 = __builtin_amdgcn_exp2f(S[qg][mt][0]);
        float p1 = __builtin_amdgcn_exp2f(S[qg][mt][1]);
        float p2 = __builtin_amdgcn_exp2f(S[qg][mt][2]);
        float p3 = __builtin_amdgcn_exp2f(S[qg][mt][3]);
        rs += (p0 + p1) + (p2 + p3);
        uint2 pk = {pk_bf16_trunc(p1, p0), pk_bf16_trunc(p3, p2)};
        *(uint2*)(ptw + (qg * 16 + l15) * 128 +
                  (((mt * 2 + (quad >> 1)) ^ (l15 & 7)) * 16 + (quad & 1) * 8)) = pk;
      }
      l_run[qg] += rs;
    }

    __builtin_amdgcn_s_setprio(1);
#pragma unroll
    for (int kk = 0; kk < 2; ++kk) {
      bf16x8 aP[2];
#pragma unroll
      for (int qg = 0; qg < 2; ++qg)
        aP[qg] = *(const bf16x8*)(ptw + (qg * 16 + l15) * 128 +
                                  (((kk * 4 + quad) ^ (l15 & 7)) * 16));
#pragma unroll
      for (int nt = 0; nt < 4; ++nt) {
        bf16x8 bV = *(const bf16x8*)(vtb + (nt * 16 + l15) * 128 +
                                     (((kk * 4 + quad) ^ (l15 & 7)) * 16));
        Oacc[0][nt] = __builtin_amdgcn_mfma_f32_16x16x32_bf16(aP[0], bV, Oacc[0][nt], 0, 0, 0);
        Oacc[1][nt] = __builtin_amdgcn_mfma_f32_16x16x32_bf16(aP[1], bV, Oacc[1][nt], 0, 0, 0);
      }
    }
    __builtin_amdgcn_s_setprio(0);
  }
#undef STAGE_KV

  // row-sum broadcast via shfl (no LDS)
#pragma unroll
  for (int qg = 0; qg < 2; ++qg) {
    l_run[qg] += __shfl_xor(l_run[qg], 16);
    l_run[qg] += __shfl_xor(l_run[qg], 32);
  }
#pragma unroll
  for (int qg = 0; qg < 2; ++qg) {
    f32x4 li;
#pragma unroll
    for (int r = 0; r < 4; ++r) li[r] = 1.0f / __shfl(l_run[qg], quad * 4 + r);
#pragma unroll
    for (int nt = 0; nt < 4; ++nt)
#pragma unroll
      for (int r = 0; r < 4; ++r) {
        size_t tok = tokbase + q0 + w * 32 + qg * 16 + quad * 4 + r;
        O[tok * DM + hh * HD + nt * 16 + l15] = f2bu(Oacc[qg][nt][r] * li[r]);
      }
  }
}

// ---------------------------------------------------------------------------
// row-wise: s = base + bf16(d0) (+ bf16(d1)); LN(s)*g+b -> outf fp32, outb opt
// ---------------------------------------------------------------------------
__global__ __launch_bounds__(256) void ln_res(
    const float* __restrict__ base, const unsigned short* __restrict__ d0,
    const unsigned short* __restrict__ d1,
    const float* __restrict__ gamma, const float* __restrict__ beta,
    float* __restrict__ outf, unsigned short* __restrict__ outb) {
  __shared__ float red[8];
  const int row = blockIdx.x, tid = threadIdx.x;
  const size_t rb = (size_t)row * DM;
  float4 xv = ((const float4*)(base + rb))[tid];
  u16x4 dv = ((const u16x4*)(d0 + rb))[tid];
  float s0 = xv.x + bu2f(dv[0]), s1 = xv.y + bu2f(dv[1]);
  float s2 = xv.z + bu2f(dv[2]), s3 = xv.w + bu2f(dv[3]);
  if (d1) {
    u16x4 ev = ((const u16x4*)(d1 + rb))[tid];
    s0 += bu2f(ev[0]); s1 += bu2f(ev[1]); s2 += bu2f(ev[2]); s3 += bu2f(ev[3]);
  }
  float t = s0 + s1 + s2 + s3;
#pragma unroll
  for (int m = 1; m < 64; m <<= 1) t += __shfl_xor(t, m);
  if ((tid & 63) == 0) red[tid >> 6] = t;
  __syncthreads();
  float mu = (red[0] + red[1] + red[2] + red[3]) * (1.0f / DM);
  float dd0 = s0 - mu, dd1 = s1 - mu, dd2 = s2 - mu, dd3 = s3 - mu;
  float v = dd0 * dd0 + dd1 * dd1 + dd2 * dd2 + dd3 * dd3;
#pragma unroll
  for (int m = 1; m < 64; m <<= 1) v += __shfl_xor(v, m);
  if ((tid & 63) == 0) red[4 + (tid >> 6)] = v;
  __syncthreads();
  float var = (red[4] + red[5] + red[6] + red[7]) * (1.0f / DM);
  float rs = rsqrtf(var + 1e-5f);
  float4 gv = ((const float4*)gamma)[tid];
  float4 bv = ((const float4*)beta)[tid];
  float o0 = dd0 * rs * gv.x + bv.x;
  float o1 = dd1 * rs * gv.y + bv.y;
  float o2 = dd2 * rs * gv.z + bv.z;
  float o3 = dd3 * rs * gv.w + bv.w;
  float4 ov = {o0, o1, o2, o3};
  ((float4*)(outf + rb))[tid] = ov;
  if (outb) {
    u16x4 ob = {f2bu(o0), f2bu(o1), f2bu(o2), f2bu(o3)};
    ((u16x4*)(outb + rb))[tid] = ob;
  }
}

// ---------------------------------------------------------------------------
extern "C" void kernel_launch(void* const* d_in, const int* in_sizes, int n_in,
                              void* d_out, int out_size, void* d_ws, size_t ws_size,
                              hipStream_t stream) {
  const float* x   = (const float*)d_in[0];
  const float* Wq  = (const float*)d_in[1];  const float* bq  = (const float*)d_in[2];
  const float* Wk  = (const float*)d_in[3];  const float* bk  = (const float*)d_in[4];
  const float* Wv  = (const float*)d_in[5];  const float* bvv = (const float*)d_in[6];
  const float* Wo  = (const float*)d_in[7];  const float* bo  = (const float*)d_in[8];
  const float* W1  = (const float*)d_in[9];  const float* b1  = (const float*)d_in[10];
  const float* W2  = (const float*)d_in[11]; const float* b2  = (const float*)d_in[12];
  const float* g1  = (const float*)d_in[13]; const float* be1 = (const float*)d_in[14];
  const float* g2  = (const float*)d_in[15]; const float* be2 = (const float*)d_in[16];

  char* ws = (char*)d_ws;
  const size_t MB = 1ull << 20;
  unsigned short* xb    = (unsigned short*)(ws + 0 * MB);    // 16MB (later hb/ffo2b alias)
  unsigned short* wqkvT = (unsigned short*)(ws + 16 * MB);   // 6MB  [3072][1024]
  unsigned short* woT   = (unsigned short*)(ws + 22 * MB);   // 2MB
  unsigned short* w1T   = (unsigned short*)(ws + 24 * MB);   // 8MB
  unsigned short* w2T   = (unsigned short*)(ws + 32 * MB);   // 8MB
  unsigned short* Qb    = (unsigned short*)(ws + 40 * MB);   // 16MB
  unsigned short* Kb    = (unsigned short*)(ws + 56 * MB);   // 16MB
  unsigned short* Vtg   = (unsigned short*)(ws + 72 * MB);   // 32MB [(b,h,d)][s]
  unsigned short* aO    = (unsigned short*)(ws + 104 * MB);  // 16MB
  unsigned short* prjb  = (unsigned short*)(ws + 120 * MB);  // 16MB bf16 partial
  unsigned short* prj2b = (unsigned short*)(ws + 40 * MB);   // 16MB alias Qb (dead post-attn)
  float*          h     = (float*)(ws + 152 * MB);           // 32MB fp32
  unsigned short* hb    = (unsigned short*)(ws + 0 * MB);    // alias xb (dead)
  unsigned short* ffm   = (unsigned short*)(ws + 40 * MB);   // 64MB alias Qb..Vtg (post-LN1)
  unsigned short* ffob  = (unsigned short*)(ws + 104 * MB);  // 16MB alias aO (dead)
  unsigned short* ffo2b = (unsigned short*)(ws + 0 * MB);    // 16MB alias hb (dead post-FF1)
  (void)ws_size; (void)in_sizes; (void)n_in; (void)out_size;

  // prep: cast x; weight transposes (B^T bf16); Wq/Wk/Wv stacked -> wqkvT
  cast_bf16<<<TOK * DM / 4 / 256, 256, 0, stream>>>(x, xb, TOK * DM / 4);
  transpose_cast4<<<dim3(DM / 32, DM / 32, 4), dim3(32, 8), 0, stream>>>(
      Wq, Wk, Wv, Wo, wqkvT, wqkvT + 1024 * 1024, wqkvT + 2048 * 1024, woT);
  transpose_cast<<<dim3(DFF / 32, DM / 32), dim3(32, 8), 0, stream>>>(W1, w1T, DM, DFF);
  transpose_cast<<<dim3(DM / 32, DFF / 32), dim3(32, 8), 0, stream>>>(W2, w2T, DFF, DM);

  // fused QKV projection (Q scaled for exp2-domain softmax; V transposed)
  gemm_qkv256<<<dim3(3 * DM / 256, TOK / 256), 512, 0, stream>>>(
      xb, wqkvT, bq, bk, bvv, Qb, Kb, Vtg);

  // attention (BQ=128, R15)
  attn_kernel<<<dim3(SEQ / 128, BATCH * NH), 256, 0, stream>>>(Qb, Kb, Vtg, aO);

  // output projection, split-K x2 -> bf16 partials
  gemm256<<<dim3(DM / 256, TOK / 256, 2), 512, 0, stream>>>(
      aO, DM, woT, DM, DM / 2, bo, prjb, prj2b, DM, 1.0f, 0, 0);
  // LN1: h = LN(x + prjb + prj2b) -> fp32 h + bf16 hb
  ln_res<<<TOK, 256, 0, stream>>>(x, prjb, prj2b, g1, be1, h, hb);

  // FF1: relu(hb @ W1 + b1) -> bf16 ffm
  gemm256<<<dim3(DFF / 256, TOK / 256, 1), 512, 0, stream>>>(
      hb, DM, w1T, DM, DM, b1, ffm, nullptr, DFF, 1.0f, 1, 0);
  // FF2 split-K -> bf16 partials (z=0 + bias -> ffob; z=1 -> ffo2b)
  gemm256<<<dim3(DM / 256, TOK / 256, 2), 512, 0, stream>>>(
      ffm, DFF, w2T, DFF, DFF / 2, b2, ffob, ffo2b, DM, 1.0f, 0, 0);

  // LN2 -> d_out (fp32): LN(h + ffob + ffo2b)
  ln_res<<<TOK, 256, 0, stream>>>(h, ffob, ffo2b, g2, be2, (float*)d_out, nullptr);
}

// Round 14
// 550.408 us; speedup vs baseline: 1.0505x; 1.0225x over previous
//
#include <hip/hip_runtime.h>
#include <hip/hip_bf16.h>

// ---------------------------------------------------------------------------
// EncoderLayer on MI355X (gfx950), round 19.
// = R18 (best, 562.8us) + h-elimination: LN1 no longer writes the fp32 h
// buffer (bf16 hb only); LN2 uses hb as its base (-48MB HBM: 32 write + 16
// net read). ln_res gains dual-precision base (fp32 or bf16) and optional
// fp32 output. ffo2b moved to 120MB (prjb, dead post-LN1) since offset 0
// now holds the live hb. GEMMs / QKV / attn / prep frozen at R18.
// ---------------------------------------------------------------------------

#define DM    1024
#define DFF   4096
#define NH    16
#define HD    64
#define BATCH 4
#define SEQ   2048
#define TOK   (BATCH * SEQ)   // 8192

typedef __attribute__((ext_vector_type(8))) __bf16 bf16x8;
typedef __attribute__((ext_vector_type(4))) float f32x4;
typedef __attribute__((ext_vector_type(16))) float f32x16;
typedef __attribute__((ext_vector_type(4))) unsigned short u16x4;
typedef __attribute__((ext_vector_type(8))) unsigned short u16x8;

typedef const __attribute__((address_space(1))) unsigned int* gas1_t;
typedef __attribute__((address_space(3))) unsigned int* las3_t;

__device__ __forceinline__ void gl_lds16(const void* g, void* l) {
  // async global->LDS, 16B per lane; LDS dest = wave-uniform base + lane*16
  __builtin_amdgcn_global_load_lds((gas1_t)g, (las3_t)l, 16, 0, 0);
}

__device__ __forceinline__ unsigned short f2bu(float x) {
  return __builtin_bit_cast(unsigned short, __float2bfloat16(x));
}

__device__ __forceinline__ float bu2f(unsigned short u) {
  return __builtin_bit_cast(float, ((unsigned)u) << 16);
}

// pack hi16(a),hi16(b) -> (b | a<<16): bf16 truncation of two floats, 1 instr
__device__ __forceinline__ unsigned pk_bf16_trunc(float hi, float lo) {
  return __builtin_amdgcn_perm(__builtin_bit_cast(unsigned, hi),
                               __builtin_bit_cast(unsigned, lo), 0x07060302u);
}

// ---------------------------------------------------------------------------
// cast fp32 -> bf16 (vectorized x4)
// ---------------------------------------------------------------------------
__global__ __launch_bounds__(256) void cast_bf16(
    const float* __restrict__ in, unsigned short* __restrict__ out, int n4) {
  int i = blockIdx.x * 256 + threadIdx.x;
  if (i >= n4) return;
  float4 v = ((const float4*)in)[i];
  u16x4 o = {f2bu(v.x), f2bu(v.y), f2bu(v.z), f2bu(v.w)};
  ((u16x4*)out)[i] = o;
}

// ---------------------------------------------------------------------------
// out[n][k] = bf16(in[k][n])   (LDS-tiled transpose, block (32,8))
// ---------------------------------------------------------------------------
__global__ __launch_bounds__(256) void transpose_cast(
    const float* __restrict__ in, unsigned short* __restrict__ out, int K, int N) {
  __shared__ float tile[32][33];
  int n0 = blockIdx.x * 32, k0 = blockIdx.y * 32;
  int tx = threadIdx.x, ty = threadIdx.y;
#pragma unroll
  for (int i = 0; i < 4; ++i)
    tile[ty + 8 * i][tx] = in[(size_t)(k0 + ty + 8 * i) * N + n0 + tx];
  __syncthreads();
#pragma unroll
  for (int i = 0; i < 4; ++i)
    out[(size_t)(n0 + ty + 8 * i) * K + k0 + tx] = f2bu(tile[tx][ty + 8 * i]);
}

// 4 square (1024x1024) weight transposes in one launch (z selects matrix)
__global__ __launch_bounds__(256) void transpose_cast4(
    const float* __restrict__ A0, const float* __restrict__ A1,
    const float* __restrict__ A2, const float* __restrict__ A3,
    unsigned short* __restrict__ O0, unsigned short* __restrict__ O1,
    unsigned short* __restrict__ O2, unsigned short* __restrict__ O3) {
  __shared__ float tile[32][33];
  const float* in; unsigned short* out;
  switch (blockIdx.z) {
    case 0: in = A0; out = O0; break;
    case 1: in = A1; out = O1; break;
    case 2: in = A2; out = O2; break;
    default: in = A3; out = O3; break;
  }
  int n0 = blockIdx.x * 32, k0 = blockIdx.y * 32;
  int tx = threadIdx.x, ty = threadIdx.y;
#pragma unroll
  for (int i = 0; i < 4; ++i)
    tile[ty + 8 * i][tx] = in[(size_t)(k0 + ty + 8 * i) * DM + n0 + tx];
  __syncthreads();
#pragma unroll
  for (int i = 0; i < 4; ++i)
    out[(size_t)(n0 + ty + 8 * i) * DM + k0 + tx] = f2bu(tile[tx][ty + 8 * i]);
}

// ---------------------------------------------------------------------------
// 256x256 GEMM mainloop, 8-phase / 2-K-tile iteration (R12, frozen).
// ---------------------------------------------------------------------------
__device__ __forceinline__ void mma8(const bf16x8 a0, const bf16x8 a1,
                                     const bf16x8 b, f32x16* c0, f32x16* c1) {
  *c0 = __builtin_amdgcn_mfma_f32_32x32x16_bf16(a0, b, *c0, 0, 0, 0);
  *c1 = __builtin_amdgcn_mfma_f32_32x32x16_bf16(a1, b, *c1, 0, 0, 0);
}

__device__ __forceinline__ void mainloop256(
    const unsigned short* __restrict__ A, int lda,
    const unsigned short* __restrict__ Bt, int ldb, int Kl,
    int m0, int n0, unsigned short* As, unsigned short* Bs,
    f32x16 acc[2][2][2]) {
  const int tid = threadIdx.x, lane = tid & 63, w = tid >> 6;
  const int l31 = lane & 31, khalf = lane >> 5;
  const int wr = w >> 2, wc = w & 3;
  const int rA0 = wr * 64 + l31, rA1 = rA0 + 32, rB = wc * 32 + l31;

  // stage source pointers: half h, instr i. granule g = (i*8+w)*64+lane;
  // row r = g>>3 (0..127), LDS chunk = g&7, source chunk = (g&7)^(r&7).
  const unsigned short* pa[2][2];
  const unsigned short* pb[2][2];
#pragma unroll
  for (int h = 0; h < 2; ++h)
#pragma unroll
    for (int i = 0; i < 2; ++i) {
      const int g = (i * 8 + w) * 64 + lane;
      const int r = g >> 3;
      const int cs = ((g & 7) ^ (r & 7)) * 8;
      pa[h][i] = A + (size_t)(m0 + h * 128 + r) * lda + cs;
      pb[h][i] = Bt + (size_t)(n0 + h * 128 + r) * ldb + cs;
    }
  const int wofsB = w * 1024;  // byte offset of this wave's 1KB DMA slice

  bf16x8 aF[2][4], b0[4], b1[4];

#define STA(BUF, H, I) \
  gl_lds16(pa[H][I], (char*)As + (BUF) * 32768 + (H) * 16384 + (I) * 8192 + wofsB)
#define STB(BUF, H, I) \
  gl_lds16(pb[H][I], (char*)Bs + (BUF) * 32768 + (H) * 16384 + (I) * 8192 + wofsB)
#define ADV_A(H) { pa[H][0] += 64; pa[H][1] += 64; }
#define ADV_B(H) { pb[H][0] += 64; pb[H][1] += 64; }

#define RD_A(BUFB, H)                                                         \
  { const char* Ah = (const char*)As + (BUFB) + (H) * 16384;                  \
    _Pragma("unroll") for (int ks = 0; ks < 4; ++ks) {                        \
      const int c = ks * 2 + khalf;                                           \
      aF[0][ks] = *(const bf16x8*)(Ah + rA0 * 128 + ((c ^ (rA0 & 7)) << 4));  \
      aF[1][ks] = *(const bf16x8*)(Ah + rA1 * 128 + ((c ^ (rA1 & 7)) << 4));  \
    } }
#define RD_B(DST, BUFB, H)                                                    \
  { const char* Bh = (const char*)Bs + (BUFB) + (H) * 16384;                  \
    _Pragma("unroll") for (int ks = 0; ks < 4; ++ks) {                        \
      const int c = ks * 2 + khalf;                                           \
      DST[ks] = *(const bf16x8*)(Bh + rB * 128 + ((c ^ (rB & 7)) << 4));      \
    } }

#define MMA4(QM, QN, BV)                                                      \
  { __builtin_amdgcn_s_setprio(1);                                           \
    _Pragma("unroll") for (int ks = 0; ks < 4; ++ks)                          \
      mma8(aF[0][ks], aF[1][ks], BV[ks], &acc[QM][QN][0], &acc[QM][QN][1]);   \
    __builtin_amdgcn_s_setprio(0); }

#define BAR asm volatile("s_barrier" ::: "memory")

// One iteration = K-tiles t (buf0) then t+1 (buf1), 8 phases.
// SL: late stages (ph2-7) on/off. G3/G7: gate strings at ph3/ph7 barrier#1.
#define ITER(SL, G3, G7)                                                      \
  /* ph0 (buf0, 0,0) */                                                       \
  RD_A(0, 0); RD_B(b0, 0, 0);                                                 \
  STA(1, 1, 0); STA(1, 1, 1); ADV_A(1);                                       \
  BAR; MMA4(0, 0, b0); BAR;                                                   \
  /* ph1 (buf0, 0,1) */                                                       \
  RD_B(b1, 0, 1);                                                             \
  STB(1, 0, 0); STB(1, 0, 1); ADV_B(0);                                       \
  BAR; MMA4(0, 1, b1); BAR;                                                   \
  /* ph2 (buf0, 1,1) */                                                       \
  RD_A(0, 1);                                                                 \
  if (SL) { STA(0, 0, 0); STA(0, 0, 1); ADV_A(0); }                           \
  BAR; MMA4(1, 1, b1); BAR;                                                   \
  /* ph3 (buf0, 1,0) — gate confirms buf1 */                                  \
  if (SL) { STB(0, 1, 0); STB(0, 1, 1); ADV_B(1); }                           \
  asm volatile(G3 ::: "memory");                                              \
  MMA4(1, 0, b0); BAR;                                                        \
  /* ph4 (buf1, 0,0) */                                                       \
  RD_A(32768, 0); RD_B(b0, 32768, 0);                                         \
  if (SL) { STA(0, 1, 0); STA(0, 1, 1); ADV_A(1); }                           \
  BAR; MMA4(0, 0, b0); BAR;                                                   \
  /* ph5 (buf1, 0,1) */                                                       \
  RD_B(b1, 32768, 1);                                                         \
  if (SL) { STB(0, 0, 0); STB(0, 0, 1); ADV_B(0); }                           \
  BAR; MMA4(0, 1, b1); BAR;                                                   \
  /* ph6 (buf1, 1,1) */                                                       \
  RD_A(32768, 1);                                                             \
  if (SL) { STA(1, 0, 0); STA(1, 0, 1); ADV_A(0); }                           \
  BAR; MMA4(1, 1, b1); BAR;                                                   \
  /* ph7 (buf1, 1,0) — gate confirms buf0 (next iter) */                      \
  if (SL) { STB(1, 1, 0); STB(1, 1, 1); ADV_B(1); }                           \
  asm volatile(G7 ::: "memory");                                              \
  MMA4(1, 0, b0); BAR;

  // prologue: tile0 full -> buf0; tile1.A0,B1 -> buf1 (= virtual ph6,ph7).
  // Gate vmcnt(4): retire tile0 (8 loads), keep tile1's 4 in flight.
  STA(0, 0, 0); STA(0, 0, 1); ADV_A(0);
  STB(0, 0, 0); STB(0, 0, 1); ADV_B(0);
  STB(0, 1, 0); STB(0, 1, 1); ADV_B(1);
  STA(0, 1, 0); STA(0, 1, 1); ADV_A(1);
  STA(1, 0, 0); STA(1, 0, 1); ADV_A(0);
  STB(1, 1, 0); STB(1, 1, 1); ADV_B(1);
  asm volatile("s_waitcnt vmcnt(4)\n\ts_barrier" ::: "memory");

  const int L = (Kl >> 6) >> 1;  // iterations of 2 K-tiles; L >= 2
  for (int i = 0; i < L - 1; ++i) {
    ITER(1, "s_waitcnt vmcnt(4)\n\ts_barrier", "s_waitcnt vmcnt(4)\n\ts_barrier");
  }
  // tail iter: ph0/ph1 still stage tile NT-1's A1,B0; no late stages;
  // ph3 gate drains everything (8 outstanding), ph7 plain barrier.
  ITER(0, "s_waitcnt vmcnt(0)\n\ts_barrier", "s_barrier");

#undef ITER
#undef BAR
#undef MMA4
#undef RD_B
#undef RD_A
#undef ADV_B
#undef ADV_A
#undef STB
#undef STA
}

// C/D layout (32x32): col = lane&31, row = (reg&3) + 8*(reg>>2) + 4*(lane>>5)
// wave quadrant (qm,qn), frag mi: rows m0+qm*128+wr*64+mi*32, cols n0+qn*128+wc*32

// XCD-aware block swizzle: blocks with equal (lin%8) land on one XCD; give
// each XCD a contiguous chunk. Requires gridDim.x*gridDim.y % 8 == 0.
__device__ __forceinline__ void xcd_swizzle(int& bx, int& by) {
  const int gx = gridDim.x, nxy = gx * gridDim.y;
  int lin = by * gx + bx;
  lin = (lin & 7) * (nxy >> 3) + (lin >> 3);
  bx = lin % gx;
  by = lin / gx;
}

// ---------------------------------------------------------------------------
// Generic C[M,N] = epi(A @ Bt^T + bias).  gridDim.z=2 -> split-K: block z
// computes K-slice [z*Kl, (z+1)*Kl) into C0/C1 (bias only in z=0).
// ---------------------------------------------------------------------------
__global__ __launch_bounds__(512, 2) void gemm256(
    const unsigned short* __restrict__ A, int lda,
    const unsigned short* __restrict__ Bt, int ldb, int Kl,
    const float* __restrict__ bias, void* __restrict__ C0,
    void* __restrict__ C1, int N, float alpha, int relu, int ofp32) {
  __shared__ unsigned short As[32768];
  __shared__ unsigned short Bs[32768];
  const int tid = threadIdx.x, lane = tid & 63, w = tid >> 6;
  const int l31 = lane & 31, khalf = lane >> 5;
  const int wr = w >> 2, wc = w & 3;
  int bx = blockIdx.x, by = blockIdx.y;
  xcd_swizzle(bx, by);
  const int m0 = by * 256, n0 = bx * 256;
  const int koff = blockIdx.z * Kl;
  void* Cout = blockIdx.z ? C1 : C0;
  const float* be = blockIdx.z ? nullptr : bias;

  f32x16 acc[2][2][2];
#pragma unroll
  for (int qm = 0; qm < 2; ++qm)
#pragma unroll
    for (int qn = 0; qn < 2; ++qn)
#pragma unroll
      for (int mi = 0; mi < 2; ++mi)
#pragma unroll
        for (int r = 0; r < 16; ++r) acc[qm][qn][mi][r] = 0.f;

  mainloop256(A + koff, lda, Bt + koff, ldb, Kl, m0, n0, As, Bs, acc);

#pragma unroll
  for (int qn = 0; qn < 2; ++qn) {
    const int col = n0 + qn * 128 + wc * 32 + l31;
    const float bvv = be ? be[col] : 0.f;
#pragma unroll
    for (int qm = 0; qm < 2; ++qm)
#pragma unroll
      for (int mi = 0; mi < 2; ++mi) {
#pragma unroll
        for (int g = 0; g < 4; ++g) {
          const int rbase = m0 + qm * 128 + wr * 64 + mi * 32 + g * 8 + khalf * 4;
#pragma unroll
          for (int r = 0; r < 4; ++r) {
            float val = alpha * (acc[qm][qn][mi][g * 4 + r] + bvv);
            if (relu) val = fmaxf(val, 0.f);
            size_t idx = (size_t)(rbase + r) * N + col;
            if (ofp32) ((float*)Cout)[idx] = val;
            else ((unsigned short*)Cout)[idx] = f2bu(val);
          }
        }
      }
  }
}

// ---------------------------------------------------------------------------
// Fused QKV gemm (256x256). N=3072: region 0: Q * QSCALE -> Qb; 1: K -> Kb;
// 2: V -> Vtg transposed per head [(b*16+h)*64+d][s] via 128KB LDS transpose
// (SH = merged As/Bs, dead after mainloop): Vtg writes become 512B runs.
// ---------------------------------------------------------------------------
#define QSCALE 0.18033688f  // (1/sqrt(64)) * log2(e): softmax runs in exp2 domain
#define VKEY(c) (((c) & 31) * 8)  // XOR row-swizzle key (bits 3-7): keeps
                                  // u16x4 writes (r%4) and u16x8 reads (r%8)
                                  // contiguous; spreads banks 8-way.

__global__ __launch_bounds__(512, 2) void gemm_qkv256(
    const unsigned short* __restrict__ A, const unsigned short* __restrict__ Bt,
    const float* __restrict__ bq, const float* __restrict__ bk,
    const float* __restrict__ bv,
    unsigned short* __restrict__ Qb, unsigned short* __restrict__ Kb,
    unsigned short* __restrict__ Vtg) {
  __shared__ unsigned short SH[65536];  // mainloop: As=SH, Bs=SH+32768;
                                        // V-epilogue: 256x256 bf16 tile
  const int tid = threadIdx.x, lane = tid & 63, w = tid >> 6;
  const int l31 = lane & 31, khalf = lane >> 5;
  const int wr = w >> 2, wc = w & 3;
  int bx = blockIdx.x, by = blockIdx.y;
  xcd_swizzle(bx, by);
  const int m0 = by * 256, n0 = bx * 256;

  f32x16 acc[2][2][2];
#pragma unroll
  for (int qm = 0; qm < 2; ++qm)
#pragma unroll
    for (int qn = 0; qn < 2; ++qn)
#pragma unroll
      for (int mi = 0; mi < 2; ++mi)
#pragma unroll
        for (int r = 0; r < 16; ++r) acc[qm][qn][mi][r] = 0.f;

  mainloop256(A, DM, Bt, DM, DM, m0, n0, SH, SH + 32768, acc);

  const int region = n0 >> 10;  // 0=Q 1=K 2=V (256-tiles never straddle)
  if (region < 2) {
    unsigned short* Out = region ? Kb : Qb;
    const float* bias = region ? bk : bq;
    const float alpha = region ? 1.0f : QSCALE;
#pragma unroll
    for (int qn = 0; qn < 2; ++qn) {
      const int col = (n0 & 1023) + qn * 128 + wc * 32 + l31;
      const float bvv = bias[col];
#pragma unroll
      for (int qm = 0; qm < 2; ++qm)
#pragma unroll
        for (int mi = 0; mi < 2; ++mi) {
#pragma unroll
          for (int g = 0; g < 4; ++g) {
            const int rbase = m0 + qm * 128 + wr * 64 + mi * 32 + g * 8 + khalf * 4;
#pragma unroll
            for (int r = 0; r < 4; ++r)
              Out[(size_t)(rbase + r) * DM + col] =
                  f2bu(alpha * (acc[qm][qn][mi][g * 4 + r] + bvv));
          }
        }
    }
  } else {
    // ---- V region: acc -> SH[dcol][srow] (swizzled), then coalesced writes
    __syncthreads();
#pragma unroll
    for (int qn = 0; qn < 2; ++qn) {
      const int cl = qn * 128 + wc * 32 + l31;          // tile-local d col
      const float bvv = bv[(n0 & 1023) + cl];
#pragma unroll
      for (int qm = 0; qm < 2; ++qm)
#pragma unroll
        for (int mi = 0; mi < 2; ++mi) {
#pragma unroll
          for (int g = 0; g < 4; ++g) {
            const int rl = qm * 128 + wr * 64 + mi * 32 + g * 8 + khalf * 4;
            u16x4 pk;
#pragma unroll
            for (int r = 0; r < 4; ++r)
              pk[r] = f2bu(acc[qm][qn][mi][g * 4 + r] + bvv);
            *(u16x4*)&SH[cl * 256 + (rl ^ VKEY(cl))] = pk;
          }
        }
    }
    __syncthreads();
    // read rows of SH, write Vtg in 512B runs (4 lanes = one 64B line/instr)
    const int b2 = m0 >> 11, s0g = m0 & 2047;
    const int jj = tid & 3;
#pragma unroll
    for (int pass = 0; pass < 2; ++pass) {
      const int dcol = (tid >> 2) + pass * 128;
      const int gcol = (n0 & 1023) + dcol;
      const int hh2 = gcol >> 6, dl2 = gcol & 63;
      unsigned short* dst =
          Vtg + ((size_t)((b2 * NH + hh2) * HD + dl2)) * SEQ + s0g;
#pragma unroll
      for (int c = 0; c < 8; ++c) {
        const int r0 = jj * 8 + c * 32;
        u16x8 v = *(const u16x8*)&SH[dcol * 256 + (r0 ^ VKEY(dcol))];
        *(u16x8*)(dst + r0) = v;
      }
    }
  }
}

// ---------------------------------------------------------------------------
// Flash attention, S^T formulation, BQ=128, NO-max exp2 softmax (R15).
// bh-locality XCD remap + setprio around MFMA clusters.
// 4-deep K/V LDS ring, counted vmcnt(8) + single raw s_barrier per KV-tile.
// ---------------------------------------------------------------------------
__global__ __launch_bounds__(256) void attn_kernel(
    const unsigned short* __restrict__ Q, const unsigned short* __restrict__ K,
    const unsigned short* __restrict__ Vtg, unsigned short* __restrict__ O) {
  __shared__ unsigned short Kt[4][64 * 64];   // [buf][kv][d] swizzled, 8KB x4
  __shared__ unsigned short Vt[4][64 * 64];   // [buf][d][kv] swizzled, 8KB x4
  __shared__ unsigned short Pt[4][32 * 64];   // per-wave [q][kv], 4KB x4

  const int tid = threadIdx.x, lane = tid & 63, w = tid >> 6;
  const int l15 = lane & 15, quad = lane >> 4;
  // bh-locality remap: launch-linear L -> XCD c = L&7 (round-robin dispatch);
  // bh = c*8 + ((L>>3)&7) pins all q-blocks of bh to XCD c; qb = L>>6.
  const int L = blockIdx.y * gridDim.x + blockIdx.x;  // 0..1023
  const int bh = (L & 7) * 8 + ((L >> 3) & 7);
  const int q0 = (L >> 6) * 128;
  const int b = bh >> 4, hh = bh & 15;
  const size_t tokbase = (size_t)b * SEQ;

  bf16x8 qf[2][2];
#pragma unroll
  for (int qg = 0; qg < 2; ++qg)
#pragma unroll
    for (int kk = 0; kk < 2; ++kk)
      qf[qg][kk] = *(const bf16x8*)(Q +
          (tokbase + q0 + w * 32 + qg * 16 + l15) * DM + hh * HD + kk * 32 + quad * 8);

  float l_run[2] = {0.f, 0.f};
  f32x4 Oacc[2][4];
#pragma unroll
  for (int qg = 0; qg < 2; ++qg)
#pragma unroll
    for (int nt = 0; nt < 4; ++nt) Oacc[qg][nt] = {0.f, 0.f, 0.f, 0.f};

  char* ptw = (char*)&Pt[w][0];

  // staging: per wave 2 K-slices + 2 V-slices (i=0,1), 16B/lane each.
  int rowS[2], csrcS[2];
#pragma unroll
  for (int i = 0; i < 2; ++i) {
    int f = (i * 4 + w) * 64 + lane;
    rowS[i] = f >> 3;
    csrcS[i] = ((f & 7) ^ (rowS[i] & 7)) * 8;
  }
  const unsigned short* kg[2];
  const unsigned short* vg[2];
#pragma unroll
  for (int i = 0; i < 2; ++i) {
    kg[i] = K + (tokbase + rowS[i]) * DM + hh * HD + csrcS[i];
    vg[i] = Vtg + ((size_t)bh * HD + rowS[i]) * SEQ + csrcS[i];
  }

#define STAGE_KV(BUF)                                                         \
  { _Pragma("unroll") for (int i = 0; i < 2; ++i) {                           \
      gl_lds16(kg[i], (char*)Kt + (BUF) * 8192 + (i * 4 + w) * 1024);         \
      gl_lds16(vg[i], (char*)Vt + (BUF) * 8192 + (i * 4 + w) * 1024);         \
      kg[i] += 64 * DM;                                                       \
      vg[i] += 64;                                                            \
    } }

  const int NT = SEQ / 64;  // 32
  // prologue: stage tiles 0 and 1
  STAGE_KV(0);
  STAGE_KV(1);

  for (int j = 0; j < NT; ++j) {
    const int buf = j & 3;
    if (j + 2 < NT) STAGE_KV((j + 2) & 3);
    // gate: retire tile j (per-wave count), then block-wide barrier
    if (j < NT - 2)
      asm volatile("s_waitcnt vmcnt(8)\n\ts_barrier" ::: "memory");
    else if (j == NT - 2)
      asm volatile("s_waitcnt vmcnt(4)\n\ts_barrier" ::: "memory");
    else
      asm volatile("s_waitcnt vmcnt(0)\n\ts_barrier" ::: "memory");

    const char* ktb = (const char*)Kt + buf * 8192;
    const char* vtb = (const char*)Vt + buf * 8192;

    f32x4 S[2][4];
#pragma unroll
    for (int qg = 0; qg < 2; ++qg)
#pragma unroll
      for (int mt = 0; mt < 4; ++mt) S[qg][mt] = {0.f, 0.f, 0.f, 0.f};
    __builtin_amdgcn_s_setprio(1);
#pragma unroll
    for (int kk = 0; kk < 2; ++kk) {
#pragma unroll
      for (int mt = 0; mt < 4; ++mt) {
        bf16x8 aK = *(const bf16x8*)(ktb + (mt * 16 + l15) * 128 +
                                     (((kk * 4 + quad) ^ (l15 & 7)) * 16));
        S[0][mt] = __builtin_amdgcn_mfma_f32_16x16x32_bf16(aK, qf[0][kk], S[0][mt], 0, 0, 0);
        S[1][mt] = __builtin_amdgcn_mfma_f32_16x16x32_bf16(aK, qf[1][kk], S[1][mt], 0, 0, 0);
      }
    }
    __builtin_amdgcn_s_setprio(0);

#pragma unroll
    for (int qg = 0; qg < 2; ++qg) {
      float rs = 0.f;
#pragma unroll
      for (int mt = 0; mt < 4; ++mt) {
        float p0 = __builtin_amdgcn_exp2f(S[qg][mt][0]);
        float p1 = __builtin_amdgcn_exp2f(S[qg][mt][1]);
        float p2 = __builtin_amdgcn_exp2f(S[qg][mt][2]);
        float p3 = __builtin_amdgcn_exp2f(S[qg][mt][3]);
        rs += (p0 + p1) + (p2 + p3);
        uint2 pk = {pk_bf16_trunc(p1, p0), pk_bf16_trunc(p3, p2)};
        *(uint2*)(ptw + (qg * 16 + l15) * 128 +
                  (((mt * 2 + (quad >> 1)) ^ (l15 & 7)) * 16 + (quad & 1) * 8)) = pk;
      }
      l_run[qg] += rs;
    }

    __builtin_amdgcn_s_setprio(1);
#pragma unroll
    for (int kk = 0; kk < 2; ++kk) {
      bf16x8 aP[2];
#pragma unroll
      for (int qg = 0; qg < 2; ++qg)
        aP[qg] = *(const bf16x8*)(ptw + (qg * 16 + l15) * 128 +
                                  (((kk * 4 + quad) ^ (l15 & 7)) * 16));
#pragma unroll
      for (int nt = 0; nt < 4; ++nt) {
        bf16x8 bV = *(const bf16x8*)(vtb + (nt * 16 + l15) * 128 +
                                     (((kk * 4 + quad) ^ (l15 & 7)) * 16));
        Oacc[0][nt] = __builtin_amdgcn_mfma_f32_16x16x32_bf16(aP[0], bV, Oacc[0][nt], 0, 0, 0);
        Oacc[1][nt] = __builtin_amdgcn_mfma_f32_16x16x32_bf16(aP[1], bV, Oacc[1][nt], 0, 0, 0);
      }
    }
    __builtin_amdgcn_s_setprio(0);
  }
#undef STAGE_KV

  // row-sum broadcast via shfl (no LDS)
#pragma unroll
  for (int qg = 0; qg < 2; ++qg) {
    l_run[qg] += __shfl_xor(l_run[qg], 16);
    l_run[qg] += __shfl_xor(l_run[qg], 32);
  }
#pragma unroll
  for (int qg = 0; qg < 2; ++qg) {
    f32x4 li;
#pragma unroll
    for (int r = 0; r < 4; ++r) li[r] = 1.0f / __shfl(l_run[qg], quad * 4 + r);
#pragma unroll
    for (int nt = 0; nt < 4; ++nt)
#pragma unroll
      for (int r = 0; r < 4; ++r) {
        size_t tok = tokbase + q0 + w * 32 + qg * 16 + quad * 4 + r;
        O[tok * DM + hh * HD + nt * 16 + l15] = f2bu(Oacc[qg][nt][r] * li[r]);
      }
  }
}

// ---------------------------------------------------------------------------
// row-wise LN over s = base + d0 (+ d1).  base is fp32 (basef) OR bf16
// (baseb) — exactly one non-null. outf (fp32) and outb (bf16) optional.
// ---------------------------------------------------------------------------
__global__ __launch_bounds__(256) void ln_res(
    const float* __restrict__ basef, const unsigned short* __restrict__ baseb,
    const unsigned short* __restrict__ d0,
    const unsigned short* __restrict__ d1,
    const float* __restrict__ gamma, const float* __restrict__ beta,
    float* __restrict__ outf, unsigned short* __restrict__ outb) {
  __shared__ float red[8];
  const int row = blockIdx.x, tid = threadIdx.x;
  const size_t rb = (size_t)row * DM;
  float s0, s1, s2, s3;
  if (basef) {
    float4 xv = ((const float4*)(basef + rb))[tid];
    s0 = xv.x; s1 = xv.y; s2 = xv.z; s3 = xv.w;
  } else {
    u16x4 xv = ((const u16x4*)(baseb + rb))[tid];
    s0 = bu2f(xv[0]); s1 = bu2f(xv[1]); s2 = bu2f(xv[2]); s3 = bu2f(xv[3]);
  }
  u16x4 dv = ((const u16x4*)(d0 + rb))[tid];
  s0 += bu2f(dv[0]); s1 += bu2f(dv[1]); s2 += bu2f(dv[2]); s3 += bu2f(dv[3]);
  if (d1) {
    u16x4 ev = ((const u16x4*)(d1 + rb))[tid];
    s0 += bu2f(ev[0]); s1 += bu2f(ev[1]); s2 += bu2f(ev[2]); s3 += bu2f(ev[3]);
  }
  float t = s0 + s1 + s2 + s3;
#pragma unroll
  for (int m = 1; m < 64; m <<= 1) t += __shfl_xor(t, m);
  if ((tid & 63) == 0) red[tid >> 6] = t;
  __syncthreads();
  float mu = (red[0] + red[1] + red[2] + red[3]) * (1.0f / DM);
  float dd0 = s0 - mu, dd1 = s1 - mu, dd2 = s2 - mu, dd3 = s3 - mu;
  float v = dd0 * dd0 + dd1 * dd1 + dd2 * dd2 + dd3 * dd3;
#pragma unroll
  for (int m = 1; m < 64; m <<= 1) v += __shfl_xor(v, m);
  if ((tid & 63) == 0) red[4 + (tid >> 6)] = v;
  __syncthreads();
  float var = (red[4] + red[5] + red[6] + red[7]) * (1.0f / DM);
  float rs = rsqrtf(var + 1e-5f);
  float4 gv = ((const float4*)gamma)[tid];
  float4 bv = ((const float4*)beta)[tid];
  float o0 = dd0 * rs * gv.x + bv.x;
  float o1 = dd1 * rs * gv.y + bv.y;
  float o2 = dd2 * rs * gv.z + bv.z;
  float o3 = dd3 * rs * gv.w + bv.w;
  if (outf) {
    float4 ov = {o0, o1, o2, o3};
    ((float4*)(outf + rb))[tid] = ov;
  }
  if (outb) {
    u16x4 ob = {f2bu(o0), f2bu(o1), f2bu(o2), f2bu(o3)};
    ((u16x4*)(outb + rb))[tid] = ob;
  }
}

// ---------------------------------------------------------------------------
extern "C" void kernel_launch(void* const* d_in, const int* in_sizes, int n_in,
                              void* d_out, int out_size, void* d_ws, size_t ws_size,
                              hipStream_t stream) {
  const float* x   = (const float*)d_in[0];
  const float* Wq  = (const float*)d_in[1];  const float* bq  = (const float*)d_in[2];
  const float* Wk  = (const float*)d_in[3];  const float* bk  = (const float*)d_in[4];
  const float* Wv  = (const float*)d_in[5];  const float* bvv = (const float*)d_in[6];
  const float* Wo  = (const float*)d_in[7];  const float* bo  = (const float*)d_in[8];
  const float* W1  = (const float*)d_in[9];  const float* b1  = (const float*)d_in[10];
  const float* W2  = (const float*)d_in[11]; const float* b2  = (const float*)d_in[12];
  const float* g1  = (const float*)d_in[13]; const float* be1 = (const float*)d_in[14];
  const float* g2  = (const float*)d_in[15]; const float* be2 = (const float*)d_in[16];

  char* ws = (char*)d_ws;
  const size_t MB = 1ull << 20;
  unsigned short* xb    = (unsigned short*)(ws + 0 * MB);    // 16MB (later hb alias)
  unsigned short* wqkvT = (unsigned short*)(ws + 16 * MB);   // 6MB  [3072][1024]
  unsigned short* woT   = (unsigned short*)(ws + 22 * MB);   // 2MB
  unsigned short* w1T   = (unsigned short*)(ws + 24 * MB);   // 8MB
  unsigned short* w2T   = (unsigned short*)(ws + 32 * MB);   // 8MB
  unsigned short* Qb    = (unsigned short*)(ws + 40 * MB);   // 16MB
  unsigned short* Kb    = (unsigned short*)(ws + 56 * MB);   // 16MB
  unsigned short* Vtg   = (unsigned short*)(ws + 72 * MB);   // 32MB [(b,h,d)][s]
  unsigned short* aO    = (unsigned short*)(ws + 104 * MB);  // 16MB
  unsigned short* prjb  = (unsigned short*)(ws + 120 * MB);  // 16MB bf16 partial
  unsigned short* prj2b = (unsigned short*)(ws + 40 * MB);   // 16MB alias Qb (dead post-attn)
  unsigned short* hb    = (unsigned short*)(ws + 0 * MB);    // alias xb (dead); LIVE thru LN2
  unsigned short* ffm   = (unsigned short*)(ws + 40 * MB);   // 64MB alias Qb..Vtg (post-LN1)
  unsigned short* ffob  = (unsigned short*)(ws + 104 * MB);  // 16MB alias aO (dead)
  unsigned short* ffo2b = (unsigned short*)(ws + 120 * MB);  // 16MB alias prjb (dead post-LN1)
  (void)ws_size; (void)in_sizes; (void)n_in; (void)out_size;

  // prep: cast x; weight transposes (B^T bf16); Wq/Wk/Wv stacked -> wqkvT
  cast_bf16<<<TOK * DM / 4 / 256, 256, 0, stream>>>(x, xb, TOK * DM / 4);
  transpose_cast4<<<dim3(DM / 32, DM / 32, 4), dim3(32, 8), 0, stream>>>(
      Wq, Wk, Wv, Wo, wqkvT, wqkvT + 1024 * 1024, wqkvT + 2048 * 1024, woT);
  transpose_cast<<<dim3(DFF / 32, DM / 32), dim3(32, 8), 0, stream>>>(W1, w1T, DM, DFF);
  transpose_cast<<<dim3(DM / 32, DFF / 32), dim3(32, 8), 0, stream>>>(W2, w2T, DFF, DM);

  // fused QKV projection (Q scaled for exp2-domain softmax; V transposed)
  gemm_qkv256<<<dim3(3 * DM / 256, TOK / 256), 512, 0, stream>>>(
      xb, wqkvT, bq, bk, bvv, Qb, Kb, Vtg);

  // attention (BQ=128)
  attn_kernel<<<dim3(SEQ / 128, BATCH * NH), 256, 0, stream>>>(Qb, Kb, Vtg, aO);

  // output projection, split-K x2 -> bf16 partials
  gemm256<<<dim3(DM / 256, TOK / 256, 2), 512, 0, stream>>>(
      aO, DM, woT, DM, DM / 2, bo, prjb, prj2b, DM, 1.0f, 0, 0);
  // LN1: hb = bf16(LN(x + prjb + prj2b))   (no fp32 h buffer)
  ln_res<<<TOK, 256, 0, stream>>>(x, nullptr, prjb, prj2b, g1, be1, nullptr, hb);

  // FF1: relu(hb @ W1 + b1) -> bf16 ffm
  gemm256<<<dim3(DFF / 256, TOK / 256, 1), 512, 0, stream>>>(
      hb, DM, w1T, DM, DM, b1, ffm, nullptr, DFF, 1.0f, 1, 0);
  // FF2 split-K -> bf16 partials (z=0 + bias -> ffob; z=1 -> ffo2b)
  gemm256<<<dim3(DM / 256, TOK / 256, 2), 512, 0, stream>>>(
      ffm, DFF, w2T, DFF, DFF / 2, b2, ffob, ffo2b, DM, 1.0f, 0, 0);

  // LN2 -> d_out (fp32): LN(hb + ffob + ffo2b)
  ln_res<<<TOK, 256, 0, stream>>>(nullptr, hb, ffob, ffo2b, g2, be2,
                                  (float*)d_out, nullptr);
}

// Round 15
// 549.321 us; speedup vs baseline: 1.0526x; 1.0020x over previous
//
#include <hip/hip_runtime.h>
#include <hip/hip_bf16.h>

// ---------------------------------------------------------------------------
// EncoderLayer on MI355X (gfx950), round 20.
// = R19 (best, 550.4us) + LN1 base read from bf16 xb instead of fp32 x
// (-16MB HBM). hb relocated 0 -> 136MB so xb stays readable (no aliasing);
// liveness: prjb@120 dead after LN1 -> ffo2b@120; 136-152 free (old h).
// GEMMs / QKV / attn / LN structure / prep frozen at R19.
// Session state: GEMM schedule (4 variants), attn (3 variants), precision
// path all measured-closed; remaining gap to peak is per-barrier overhead
// at 1 block/CU (128KB LDS + 256 reg/wave pin), not a HW roofline.
// ---------------------------------------------------------------------------

#define DM    1024
#define DFF   4096
#define NH    16
#define HD    64
#define BATCH 4
#define SEQ   2048
#define TOK   (BATCH * SEQ)   // 8192

typedef __attribute__((ext_vector_type(8))) __bf16 bf16x8;
typedef __attribute__((ext_vector_type(4))) float f32x4;
typedef __attribute__((ext_vector_type(16))) float f32x16;
typedef __attribute__((ext_vector_type(4))) unsigned short u16x4;
typedef __attribute__((ext_vector_type(8))) unsigned short u16x8;

typedef const __attribute__((address_space(1))) unsigned int* gas1_t;
typedef __attribute__((address_space(3))) unsigned int* las3_t;

__device__ __forceinline__ void gl_lds16(const void* g, void* l) {
  // async global->LDS, 16B per lane; LDS dest = wave-uniform base + lane*16
  __builtin_amdgcn_global_load_lds((gas1_t)g, (las3_t)l, 16, 0, 0);
}

__device__ __forceinline__ unsigned short f2bu(float x) {
  return __builtin_bit_cast(unsigned short, __float2bfloat16(x));
}

__device__ __forceinline__ float bu2f(unsigned short u) {
  return __builtin_bit_cast(float, ((unsigned)u) << 16);
}

// pack hi16(a),hi16(b) -> (b | a<<16): bf16 truncation of two floats, 1 instr
__device__ __forceinline__ unsigned pk_bf16_trunc(float hi, float lo) {
  return __builtin_amdgcn_perm(__builtin_bit_cast(unsigned, hi),
                               __builtin_bit_cast(unsigned, lo), 0x07060302u);
}

// ---------------------------------------------------------------------------
// cast fp32 -> bf16 (vectorized x4)
// ---------------------------------------------------------------------------
__global__ __launch_bounds__(256) void cast_bf16(
    const float* __restrict__ in, unsigned short* __restrict__ out, int n4) {
  int i = blockIdx.x * 256 + threadIdx.x;
  if (i >= n4) return;
  float4 v = ((const float4*)in)[i];
  u16x4 o = {f2bu(v.x), f2bu(v.y), f2bu(v.z), f2bu(v.w)};
  ((u16x4*)out)[i] = o;
}

// ---------------------------------------------------------------------------
// out[n][k] = bf16(in[k][n])   (LDS-tiled transpose, block (32,8))
// ---------------------------------------------------------------------------
__global__ __launch_bounds__(256) void transpose_cast(
    const float* __restrict__ in, unsigned short* __restrict__ out, int K, int N) {
  __shared__ float tile[32][33];
  int n0 = blockIdx.x * 32, k0 = blockIdx.y * 32;
  int tx = threadIdx.x, ty = threadIdx.y;
#pragma unroll
  for (int i = 0; i < 4; ++i)
    tile[ty + 8 * i][tx] = in[(size_t)(k0 + ty + 8 * i) * N + n0 + tx];
  __syncthreads();
#pragma unroll
  for (int i = 0; i < 4; ++i)
    out[(size_t)(n0 + ty + 8 * i) * K + k0 + tx] = f2bu(tile[tx][ty + 8 * i]);
}

// 4 square (1024x1024) weight transposes in one launch (z selects matrix)
__global__ __launch_bounds__(256) void transpose_cast4(
    const float* __restrict__ A0, const float* __restrict__ A1,
    const float* __restrict__ A2, const float* __restrict__ A3,
    unsigned short* __restrict__ O0, unsigned short* __restrict__ O1,
    unsigned short* __restrict__ O2, unsigned short* __restrict__ O3) {
  __shared__ float tile[32][33];
  const float* in; unsigned short* out;
  switch (blockIdx.z) {
    case 0: in = A0; out = O0; break;
    case 1: in = A1; out = O1; break;
    case 2: in = A2; out = O2; break;
    default: in = A3; out = O3; break;
  }
  int n0 = blockIdx.x * 32, k0 = blockIdx.y * 32;
  int tx = threadIdx.x, ty = threadIdx.y;
#pragma unroll
  for (int i = 0; i < 4; ++i)
    tile[ty + 8 * i][tx] = in[(size_t)(k0 + ty + 8 * i) * DM + n0 + tx];
  __syncthreads();
#pragma unroll
  for (int i = 0; i < 4; ++i)
    out[(size_t)(n0 + ty + 8 * i) * DM + k0 + tx] = f2bu(tile[tx][ty + 8 * i]);
}

// ---------------------------------------------------------------------------
// 256x256 GEMM mainloop, 8-phase / 2-K-tile iteration (R12, frozen).
// ---------------------------------------------------------------------------
__device__ __forceinline__ void mma8(const bf16x8 a0, const bf16x8 a1,
                                     const bf16x8 b, f32x16* c0, f32x16* c1) {
  *c0 = __builtin_amdgcn_mfma_f32_32x32x16_bf16(a0, b, *c0, 0, 0, 0);
  *c1 = __builtin_amdgcn_mfma_f32_32x32x16_bf16(a1, b, *c1, 0, 0, 0);
}

__device__ __forceinline__ void mainloop256(
    const unsigned short* __restrict__ A, int lda,
    const unsigned short* __restrict__ Bt, int ldb, int Kl,
    int m0, int n0, unsigned short* As, unsigned short* Bs,
    f32x16 acc[2][2][2]) {
  const int tid = threadIdx.x, lane = tid & 63, w = tid >> 6;
  const int l31 = lane & 31, khalf = lane >> 5;
  const int wr = w >> 2, wc = w & 3;
  const int rA0 = wr * 64 + l31, rA1 = rA0 + 32, rB = wc * 32 + l31;

  // stage source pointers: half h, instr i. granule g = (i*8+w)*64+lane;
  // row r = g>>3 (0..127), LDS chunk = g&7, source chunk = (g&7)^(r&7).
  const unsigned short* pa[2][2];
  const unsigned short* pb[2][2];
#pragma unroll
  for (int h = 0; h < 2; ++h)
#pragma unroll
    for (int i = 0; i < 2; ++i) {
      const int g = (i * 8 + w) * 64 + lane;
      const int r = g >> 3;
      const int cs = ((g & 7) ^ (r & 7)) * 8;
      pa[h][i] = A + (size_t)(m0 + h * 128 + r) * lda + cs;
      pb[h][i] = Bt + (size_t)(n0 + h * 128 + r) * ldb + cs;
    }
  const int wofsB = w * 1024;  // byte offset of this wave's 1KB DMA slice

  bf16x8 aF[2][4], b0[4], b1[4];

#define STA(BUF, H, I) \
  gl_lds16(pa[H][I], (char*)As + (BUF) * 32768 + (H) * 16384 + (I) * 8192 + wofsB)
#define STB(BUF, H, I) \
  gl_lds16(pb[H][I], (char*)Bs + (BUF) * 32768 + (H) * 16384 + (I) * 8192 + wofsB)
#define ADV_A(H) { pa[H][0] += 64; pa[H][1] += 64; }
#define ADV_B(H) { pb[H][0] += 64; pb[H][1] += 64; }

#define RD_A(BUFB, H)                                                         \
  { const char* Ah = (const char*)As + (BUFB) + (H) * 16384;                  \
    _Pragma("unroll") for (int ks = 0; ks < 4; ++ks) {                        \
      const int c = ks * 2 + khalf;                                           \
      aF[0][ks] = *(const bf16x8*)(Ah + rA0 * 128 + ((c ^ (rA0 & 7)) << 4));  \
      aF[1][ks] = *(const bf16x8*)(Ah + rA1 * 128 + ((c ^ (rA1 & 7)) << 4));  \
    } }
#define RD_B(DST, BUFB, H)                                                    \
  { const char* Bh = (const char*)Bs + (BUFB) + (H) * 16384;                  \
    _Pragma("unroll") for (int ks = 0; ks < 4; ++ks) {                        \
      const int c = ks * 2 + khalf;                                           \
      DST[ks] = *(const bf16x8*)(Bh + rB * 128 + ((c ^ (rB & 7)) << 4));      \
    } }

#define MMA4(QM, QN, BV)                                                      \
  { __builtin_amdgcn_s_setprio(1);                                           \
    _Pragma("unroll") for (int ks = 0; ks < 4; ++ks)                          \
      mma8(aF[0][ks], aF[1][ks], BV[ks], &acc[QM][QN][0], &acc[QM][QN][1]);   \
    __builtin_amdgcn_s_setprio(0); }

#define BAR asm volatile("s_barrier" ::: "memory")

// One iteration = K-tiles t (buf0) then t+1 (buf1), 8 phases.
// SL: late stages (ph2-7) on/off. G3/G7: gate strings at ph3/ph7 barrier#1.
#define ITER(SL, G3, G7)                                                      \
  /* ph0 (buf0, 0,0) */                                                       \
  RD_A(0, 0); RD_B(b0, 0, 0);                                                 \
  STA(1, 1, 0); STA(1, 1, 1); ADV_A(1);                                       \
  BAR; MMA4(0, 0, b0); BAR;                                                   \
  /* ph1 (buf0, 0,1) */                                                       \
  RD_B(b1, 0, 1);                                                             \
  STB(1, 0, 0); STB(1, 0, 1); ADV_B(0);                                       \
  BAR; MMA4(0, 1, b1); BAR;                                                   \
  /* ph2 (buf0, 1,1) */                                                       \
  RD_A(0, 1);                                                                 \
  if (SL) { STA(0, 0, 0); STA(0, 0, 1); ADV_A(0); }                           \
  BAR; MMA4(1, 1, b1); BAR;                                                   \
  /* ph3 (buf0, 1,0) — gate confirms buf1 */                                  \
  if (SL) { STB(0, 1, 0); STB(0, 1, 1); ADV_B(1); }                           \
  asm volatile(G3 ::: "memory");                                              \
  MMA4(1, 0, b0); BAR;                                                        \
  /* ph4 (buf1, 0,0) */                                                       \
  RD_A(32768, 0); RD_B(b0, 32768, 0);                                         \
  if (SL) { STA(0, 1, 0); STA(0, 1, 1); ADV_A(1); }                           \
  BAR; MMA4(0, 0, b0); BAR;                                                   \
  /* ph5 (buf1, 0,1) */                                                       \
  RD_B(b1, 32768, 1);                                                         \
  if (SL) { STB(0, 0, 0); STB(0, 0, 1); ADV_B(0); }                           \
  BAR; MMA4(0, 1, b1); BAR;                                                   \
  /* ph6 (buf1, 1,1) */                                                       \
  RD_A(32768, 1);                                                             \
  if (SL) { STA(1, 0, 0); STA(1, 0, 1); ADV_A(0); }                           \
  BAR; MMA4(1, 1, b1); BAR;                                                   \
  /* ph7 (buf1, 1,0) — gate confirms buf0 (next iter) */                      \
  if (SL) { STB(1, 1, 0); STB(1, 1, 1); ADV_B(1); }                           \
  asm volatile(G7 ::: "memory");                                              \
  MMA4(1, 0, b0); BAR;

  // prologue: tile0 full -> buf0; tile1.A0,B1 -> buf1 (= virtual ph6,ph7).
  // Gate vmcnt(4): retire tile0 (8 loads), keep tile1's 4 in flight.
  STA(0, 0, 0); STA(0, 0, 1); ADV_A(0);
  STB(0, 0, 0); STB(0, 0, 1); ADV_B(0);
  STB(0, 1, 0); STB(0, 1, 1); ADV_B(1);
  STA(0, 1, 0); STA(0, 1, 1); ADV_A(1);
  STA(1, 0, 0); STA(1, 0, 1); ADV_A(0);
  STB(1, 1, 0); STB(1, 1, 1); ADV_B(1);
  asm volatile("s_waitcnt vmcnt(4)\n\ts_barrier" ::: "memory");

  const int L = (Kl >> 6) >> 1;  // iterations of 2 K-tiles; L >= 2
  for (int i = 0; i < L - 1; ++i) {
    ITER(1, "s_waitcnt vmcnt(4)\n\ts_barrier", "s_waitcnt vmcnt(4)\n\ts_barrier");
  }
  // tail iter: ph0/ph1 still stage tile NT-1's A1,B0; no late stages;
  // ph3 gate drains everything (8 outstanding), ph7 plain barrier.
  ITER(0, "s_waitcnt vmcnt(0)\n\ts_barrier", "s_barrier");

#undef ITER
#undef BAR
#undef MMA4
#undef RD_B
#undef RD_A
#undef ADV_B
#undef ADV_A
#undef STB
#undef STA
}

// C/D layout (32x32): col = lane&31, row = (reg&3) + 8*(reg>>2) + 4*(lane>>5)
// wave quadrant (qm,qn), frag mi: rows m0+qm*128+wr*64+mi*32, cols n0+qn*128+wc*32

// XCD-aware block swizzle: blocks with equal (lin%8) land on one XCD; give
// each XCD a contiguous chunk. Requires gridDim.x*gridDim.y % 8 == 0.
__device__ __forceinline__ void xcd_swizzle(int& bx, int& by) {
  const int gx = gridDim.x, nxy = gx * gridDim.y;
  int lin = by * gx + bx;
  lin = (lin & 7) * (nxy >> 3) + (lin >> 3);
  bx = lin % gx;
  by = lin / gx;
}

// ---------------------------------------------------------------------------
// Generic C[M,N] = epi(A @ Bt^T + bias).  gridDim.z=2 -> split-K: block z
// computes K-slice [z*Kl, (z+1)*Kl) into C0/C1 (bias only in z=0).
// ---------------------------------------------------------------------------
__global__ __launch_bounds__(512, 2) void gemm256(
    const unsigned short* __restrict__ A, int lda,
    const unsigned short* __restrict__ Bt, int ldb, int Kl,
    const float* __restrict__ bias, void* __restrict__ C0,
    void* __restrict__ C1, int N, float alpha, int relu, int ofp32) {
  __shared__ unsigned short As[32768];
  __shared__ unsigned short Bs[32768];
  const int tid = threadIdx.x, lane = tid & 63, w = tid >> 6;
  const int l31 = lane & 31, khalf = lane >> 5;
  const int wr = w >> 2, wc = w & 3;
  int bx = blockIdx.x, by = blockIdx.y;
  xcd_swizzle(bx, by);
  const int m0 = by * 256, n0 = bx * 256;
  const int koff = blockIdx.z * Kl;
  void* Cout = blockIdx.z ? C1 : C0;
  const float* be = blockIdx.z ? nullptr : bias;

  f32x16 acc[2][2][2];
#pragma unroll
  for (int qm = 0; qm < 2; ++qm)
#pragma unroll
    for (int qn = 0; qn < 2; ++qn)
#pragma unroll
      for (int mi = 0; mi < 2; ++mi)
#pragma unroll
        for (int r = 0; r < 16; ++r) acc[qm][qn][mi][r] = 0.f;

  mainloop256(A + koff, lda, Bt + koff, ldb, Kl, m0, n0, As, Bs, acc);

#pragma unroll
  for (int qn = 0; qn < 2; ++qn) {
    const int col = n0 + qn * 128 + wc * 32 + l31;
    const float bvv = be ? be[col] : 0.f;
#pragma unroll
    for (int qm = 0; qm < 2; ++qm)
#pragma unroll
      for (int mi = 0; mi < 2; ++mi) {
#pragma unroll
        for (int g = 0; g < 4; ++g) {
          const int rbase = m0 + qm * 128 + wr * 64 + mi * 32 + g * 8 + khalf * 4;
#pragma unroll
          for (int r = 0; r < 4; ++r) {
            float val = alpha * (acc[qm][qn][mi][g * 4 + r] + bvv);
            if (relu) val = fmaxf(val, 0.f);
            size_t idx = (size_t)(rbase + r) * N + col;
            if (ofp32) ((float*)Cout)[idx] = val;
            else ((unsigned short*)Cout)[idx] = f2bu(val);
          }
        }
      }
  }
}

// ---------------------------------------------------------------------------
// Fused QKV gemm (256x256). N=3072: region 0: Q * QSCALE -> Qb; 1: K -> Kb;
// 2: V -> Vtg transposed per head [(b*16+h)*64+d][s] via 128KB LDS transpose
// (SH = merged As/Bs, dead after mainloop): Vtg writes become 512B runs.
// ---------------------------------------------------------------------------
#define QSCALE 0.18033688f  // (1/sqrt(64)) * log2(e): softmax runs in exp2 domain
#define VKEY(c) (((c) & 31) * 8)  // XOR row-swizzle key (bits 3-7): keeps
                                  // u16x4 writes (r%4) and u16x8 reads (r%8)
                                  // contiguous; spreads banks 8-way.

__global__ __launch_bounds__(512, 2) void gemm_qkv256(
    const unsigned short* __restrict__ A, const unsigned short* __restrict__ Bt,
    const float* __restrict__ bq, const float* __restrict__ bk,
    const float* __restrict__ bv,
    unsigned short* __restrict__ Qb, unsigned short* __restrict__ Kb,
    unsigned short* __restrict__ Vtg) {
  __shared__ unsigned short SH[65536];  // mainloop: As=SH, Bs=SH+32768;
                                        // V-epilogue: 256x256 bf16 tile
  const int tid = threadIdx.x, lane = tid & 63, w = tid >> 6;
  const int l31 = lane & 31, khalf = lane >> 5;
  const int wr = w >> 2, wc = w & 3;
  int bx = blockIdx.x, by = blockIdx.y;
  xcd_swizzle(bx, by);
  const int m0 = by * 256, n0 = bx * 256;

  f32x16 acc[2][2][2];
#pragma unroll
  for (int qm = 0; qm < 2; ++qm)
#pragma unroll
    for (int qn = 0; qn < 2; ++qn)
#pragma unroll
      for (int mi = 0; mi < 2; ++mi)
#pragma unroll
        for (int r = 0; r < 16; ++r) acc[qm][qn][mi][r] = 0.f;

  mainloop256(A, DM, Bt, DM, DM, m0, n0, SH, SH + 32768, acc);

  const int region = n0 >> 10;  // 0=Q 1=K 2=V (256-tiles never straddle)
  if (region < 2) {
    unsigned short* Out = region ? Kb : Qb;
    const float* bias = region ? bk : bq;
    const float alpha = region ? 1.0f : QSCALE;
#pragma unroll
    for (int qn = 0; qn < 2; ++qn) {
      const int col = (n0 & 1023) + qn * 128 + wc * 32 + l31;
      const float bvv = bias[col];
#pragma unroll
      for (int qm = 0; qm < 2; ++qm)
#pragma unroll
        for (int mi = 0; mi < 2; ++mi) {
#pragma unroll
          for (int g = 0; g < 4; ++g) {
            const int rbase = m0 + qm * 128 + wr * 64 + mi * 32 + g * 8 + khalf * 4;
#pragma unroll
            for (int r = 0; r < 4; ++r)
              Out[(size_t)(rbase + r) * DM + col] =
                  f2bu(alpha * (acc[qm][qn][mi][g * 4 + r] + bvv));
          }
        }
    }
  } else {
    // ---- V region: acc -> SH[dcol][srow] (swizzled), then coalesced writes
    __syncthreads();
#pragma unroll
    for (int qn = 0; qn < 2; ++qn) {
      const int cl = qn * 128 + wc * 32 + l31;          // tile-local d col
      const float bvv = bv[(n0 & 1023) + cl];
#pragma unroll
      for (int qm = 0; qm < 2; ++qm)
#pragma unroll
        for (int mi = 0; mi < 2; ++mi) {
#pragma unroll
          for (int g = 0; g < 4; ++g) {
            const int rl = qm * 128 + wr * 64 + mi * 32 + g * 8 + khalf * 4;
            u16x4 pk;
#pragma unroll
            for (int r = 0; r < 4; ++r)
              pk[r] = f2bu(acc[qm][qn][mi][g * 4 + r] + bvv);
            *(u16x4*)&SH[cl * 256 + (rl ^ VKEY(cl))] = pk;
          }
        }
    }
    __syncthreads();
    // read rows of SH, write Vtg in 512B runs (4 lanes = one 64B line/instr)
    const int b2 = m0 >> 11, s0g = m0 & 2047;
    const int jj = tid & 3;
#pragma unroll
    for (int pass = 0; pass < 2; ++pass) {
      const int dcol = (tid >> 2) + pass * 128;
      const int gcol = (n0 & 1023) + dcol;
      const int hh2 = gcol >> 6, dl2 = gcol & 63;
      unsigned short* dst =
          Vtg + ((size_t)((b2 * NH + hh2) * HD + dl2)) * SEQ + s0g;
#pragma unroll
      for (int c = 0; c < 8; ++c) {
        const int r0 = jj * 8 + c * 32;
        u16x8 v = *(const u16x8*)&SH[dcol * 256 + (r0 ^ VKEY(dcol))];
        *(u16x8*)(dst + r0) = v;
      }
    }
  }
}

// ---------------------------------------------------------------------------
// Flash attention, S^T formulation, BQ=128, NO-max exp2 softmax (R15).
// bh-locality XCD remap + setprio around MFMA clusters.
// 4-deep K/V LDS ring, counted vmcnt(8) + single raw s_barrier per KV-tile.
// ---------------------------------------------------------------------------
__global__ __launch_bounds__(256) void attn_kernel(
    const unsigned short* __restrict__ Q, const unsigned short* __restrict__ K,
    const unsigned short* __restrict__ Vtg, unsigned short* __restrict__ O) {
  __shared__ unsigned short Kt[4][64 * 64];   // [buf][kv][d] swizzled, 8KB x4
  __shared__ unsigned short Vt[4][64 * 64];   // [buf][d][kv] swizzled, 8KB x4
  __shared__ unsigned short Pt[4][32 * 64];   // per-wave [q][kv], 4KB x4

  const int tid = threadIdx.x, lane = tid & 63, w = tid >> 6;
  const int l15 = lane & 15, quad = lane >> 4;
  // bh-locality remap: launch-linear L -> XCD c = L&7 (round-robin dispatch);
  // bh = c*8 + ((L>>3)&7) pins all q-blocks of bh to XCD c; qb = L>>6.
  const int L = blockIdx.y * gridDim.x + blockIdx.x;  // 0..1023
  const int bh = (L & 7) * 8 + ((L >> 3) & 7);
  const int q0 = (L >> 6) * 128;
  const int b = bh >> 4, hh = bh & 15;
  const size_t tokbase = (size_t)b * SEQ;

  bf16x8 qf[2][2];
#pragma unroll
  for (int qg = 0; qg < 2; ++qg)
#pragma unroll
    for (int kk = 0; kk < 2; ++kk)
      qf[qg][kk] = *(const bf16x8*)(Q +
          (tokbase + q0 + w * 32 + qg * 16 + l15) * DM + hh * HD + kk * 32 + quad * 8);

  float l_run[2] = {0.f, 0.f};
  f32x4 Oacc[2][4];
#pragma unroll
  for (int qg = 0; qg < 2; ++qg)
#pragma unroll
    for (int nt = 0; nt < 4; ++nt) Oacc[qg][nt] = {0.f, 0.f, 0.f, 0.f};

  char* ptw = (char*)&Pt[w][0];

  // staging: per wave 2 K-slices + 2 V-slices (i=0,1), 16B/lane each.
  int rowS[2], csrcS[2];
#pragma unroll
  for (int i = 0; i < 2; ++i) {
    int f = (i * 4 + w) * 64 + lane;
    rowS[i] = f >> 3;
    csrcS[i] = ((f & 7) ^ (rowS[i] & 7)) * 8;
  }
  const unsigned short* kg[2];
  const unsigned short* vg[2];
#pragma unroll
  for (int i = 0; i < 2; ++i) {
    kg[i] = K + (tokbase + rowS[i]) * DM + hh * HD + csrcS[i];
    vg[i] = Vtg + ((size_t)bh * HD + rowS[i]) * SEQ + csrcS[i];
  }

#define STAGE_KV(BUF)                                                         \
  { _Pragma("unroll") for (int i = 0; i < 2; ++i) {                           \
      gl_lds16(kg[i], (char*)Kt + (BUF) * 8192 + (i * 4 + w) * 1024);         \
      gl_lds16(vg[i], (char*)Vt + (BUF) * 8192 + (i * 4 + w) * 1024);         \
      kg[i] += 64 * DM;                                                       \
      vg[i] += 64;                                                            \
    } }

  const int NT = SEQ / 64;  // 32
  // prologue: stage tiles 0 and 1
  STAGE_KV(0);
  STAGE_KV(1);

  for (int j = 0; j < NT; ++j) {
    const int buf = j & 3;
    if (j + 2 < NT) STAGE_KV((j + 2) & 3);
    // gate: retire tile j (per-wave count), then block-wide barrier
    if (j < NT - 2)
      asm volatile("s_waitcnt vmcnt(8)\n\ts_barrier" ::: "memory");
    else if (j == NT - 2)
      asm volatile("s_waitcnt vmcnt(4)\n\ts_barrier" ::: "memory");
    else
      asm volatile("s_waitcnt vmcnt(0)\n\ts_barrier" ::: "memory");

    const char* ktb = (const char*)Kt + buf * 8192;
    const char* vtb = (const char*)Vt + buf * 8192;

    f32x4 S[2][4];
#pragma unroll
    for (int qg = 0; qg < 2; ++qg)
#pragma unroll
      for (int mt = 0; mt < 4; ++mt) S[qg][mt] = {0.f, 0.f, 0.f, 0.f};
    __builtin_amdgcn_s_setprio(1);
#pragma unroll
    for (int kk = 0; kk < 2; ++kk) {
#pragma unroll
      for (int mt = 0; mt < 4; ++mt) {
        bf16x8 aK = *(const bf16x8*)(ktb + (mt * 16 + l15) * 128 +
                                     (((kk * 4 + quad) ^ (l15 & 7)) * 16));
        S[0][mt] = __builtin_amdgcn_mfma_f32_16x16x32_bf16(aK, qf[0][kk], S[0][mt], 0, 0, 0);
        S[1][mt] = __builtin_amdgcn_mfma_f32_16x16x32_bf16(aK, qf[1][kk], S[1][mt], 0, 0, 0);
      }
    }
    __builtin_amdgcn_s_setprio(0);

#pragma unroll
    for (int qg = 0; qg < 2; ++qg) {
      float rs = 0.f;
#pragma unroll
      for (int mt = 0; mt < 4; ++mt) {
        float p0 = __builtin_amdgcn_exp2f(S[qg][mt][0]);
        float p1 = __builtin_amdgcn_exp2f(S[qg][mt][1]);
        float p2 = __builtin_amdgcn_exp2f(S[qg][mt][2]);
        float p3 = __builtin_amdgcn_exp2f(S[qg][mt][3]);
        rs += (p0 + p1) + (p2 + p3);
        uint2 pk = {pk_bf16_trunc(p1, p0), pk_bf16_trunc(p3, p2)};
        *(uint2*)(ptw + (qg * 16 + l15) * 128 +
                  (((mt * 2 + (quad >> 1)) ^ (l15 & 7)) * 16 + (quad & 1) * 8)) = pk;
      }
      l_run[qg] += rs;
    }

    __builtin_amdgcn_s_setprio(1);
#pragma unroll
    for (int kk = 0; kk < 2; ++kk) {
      bf16x8 aP[2];
#pragma unroll
      for (int qg = 0; qg < 2; ++qg)
        aP[qg] = *(const bf16x8*)(ptw + (qg * 16 + l15) * 128 +
                                  (((kk * 4 + quad) ^ (l15 & 7)) * 16));
#pragma unroll
      for (int nt = 0; nt < 4; ++nt) {
        bf16x8 bV = *(const bf16x8*)(vtb + (nt * 16 + l15) * 128 +
                                     (((kk * 4 + quad) ^ (l15 & 7)) * 16));
        Oacc[0][nt] = __builtin_amdgcn_mfma_f32_16x16x32_bf16(aP[0], bV, Oacc[0][nt], 0, 0, 0);
        Oacc[1][nt] = __builtin_amdgcn_mfma_f32_16x16x32_bf16(aP[1], bV, Oacc[1][nt], 0, 0, 0);
      }
    }
    __builtin_amdgcn_s_setprio(0);
  }
#undef STAGE_KV

  // row-sum broadcast via shfl (no LDS)
#pragma unroll
  for (int qg = 0; qg < 2; ++qg) {
    l_run[qg] += __shfl_xor(l_run[qg], 16);
    l_run[qg] += __shfl_xor(l_run[qg], 32);
  }
#pragma unroll
  for (int qg = 0; qg < 2; ++qg) {
    f32x4 li;
#pragma unroll
    for (int r = 0; r < 4; ++r) li[r] = 1.0f / __shfl(l_run[qg], quad * 4 + r);
#pragma unroll
    for (int nt = 0; nt < 4; ++nt)
#pragma unroll
      for (int r = 0; r < 4; ++r) {
        size_t tok = tokbase + q0 + w * 32 + qg * 16 + quad * 4 + r;
        O[tok * DM + hh * HD + nt * 16 + l15] = f2bu(Oacc[qg][nt][r] * li[r]);
      }
  }
}

// ---------------------------------------------------------------------------
// row-wise LN over s = base + d0 (+ d1).  base is fp32 (basef) OR bf16
// (baseb) — exactly one non-null. outf (fp32) and outb (bf16) optional.
// ---------------------------------------------------------------------------
__global__ __launch_bounds__(256) void ln_res(
    const float* __restrict__ basef, const unsigned short* __restrict__ baseb,
    const unsigned short* __restrict__ d0,
    const unsigned short* __restrict__ d1,
    const float* __restrict__ gamma, const float* __restrict__ beta,
    float* __restrict__ outf, unsigned short* __restrict__ outb) {
  __shared__ float red[8];
  const int row = blockIdx.x, tid = threadIdx.x;
  const size_t rb = (size_t)row * DM;
  float s0, s1, s2, s3;
  if (basef) {
    float4 xv = ((const float4*)(basef + rb))[tid];
    s0 = xv.x; s1 = xv.y; s2 = xv.z; s3 = xv.w;
  } else {
    u16x4 xv = ((const u16x4*)(baseb + rb))[tid];
    s0 = bu2f(xv[0]); s1 = bu2f(xv[1]); s2 = bu2f(xv[2]); s3 = bu2f(xv[3]);
  }
  u16x4 dv = ((const u16x4*)(d0 + rb))[tid];
  s0 += bu2f(dv[0]); s1 += bu2f(dv[1]); s2 += bu2f(dv[2]); s3 += bu2f(dv[3]);
  if (d1) {
    u16x4 ev = ((const u16x4*)(d1 + rb))[tid];
    s0 += bu2f(ev[0]); s1 += bu2f(ev[1]); s2 += bu2f(ev[2]); s3 += bu2f(ev[3]);
  }
  float t = s0 + s1 + s2 + s3;
#pragma unroll
  for (int m = 1; m < 64; m <<= 1) t += __shfl_xor(t, m);
  if ((tid & 63) == 0) red[tid >> 6] = t;
  __syncthreads();
  float mu = (red[0] + red[1] + red[2] + red[3]) * (1.0f / DM);
  float dd0 = s0 - mu, dd1 = s1 - mu, dd2 = s2 - mu, dd3 = s3 - mu;
  float v = dd0 * dd0 + dd1 * dd1 + dd2 * dd2 + dd3 * dd3;
#pragma unroll
  for (int m = 1; m < 64; m <<= 1) v += __shfl_xor(v, m);
  if ((tid & 63) == 0) red[4 + (tid >> 6)] = v;
  __syncthreads();
  float var = (red[4] + red[5] + red[6] + red[7]) * (1.0f / DM);
  float rs = rsqrtf(var + 1e-5f);
  float4 gv = ((const float4*)gamma)[tid];
  float4 bv = ((const float4*)beta)[tid];
  float o0 = dd0 * rs * gv.x + bv.x;
  float o1 = dd1 * rs * gv.y + bv.y;
  float o2 = dd2 * rs * gv.z + bv.z;
  float o3 = dd3 * rs * gv.w + bv.w;
  if (outf) {
    float4 ov = {o0, o1, o2, o3};
    ((float4*)(outf + rb))[tid] = ov;
  }
  if (outb) {
    u16x4 ob = {f2bu(o0), f2bu(o1), f2bu(o2), f2bu(o3)};
    ((u16x4*)(outb + rb))[tid] = ob;
  }
}

// ---------------------------------------------------------------------------
extern "C" void kernel_launch(void* const* d_in, const int* in_sizes, int n_in,
                              void* d_out, int out_size, void* d_ws, size_t ws_size,
                              hipStream_t stream) {
  const float* x   = (const float*)d_in[0];
  const float* Wq  = (const float*)d_in[1];  const float* bq  = (const float*)d_in[2];
  const float* Wk  = (const float*)d_in[3];  const float* bk  = (const float*)d_in[4];
  const float* Wv  = (const float*)d_in[5];  const float* bvv = (const float*)d_in[6];
  const float* Wo  = (const float*)d_in[7];  const float* bo  = (const float*)d_in[8];
  const float* W1  = (const float*)d_in[9];  const float* b1  = (const float*)d_in[10];
  const float* W2  = (const float*)d_in[11]; const float* b2  = (const float*)d_in[12];
  const float* g1  = (const float*)d_in[13]; const float* be1 = (const float*)d_in[14];
  const float* g2  = (const float*)d_in[15]; const float* be2 = (const float*)d_in[16];

  char* ws = (char*)d_ws;
  const size_t MB = 1ull << 20;
  unsigned short* xb    = (unsigned short*)(ws + 0 * MB);    // 16MB; LIVE thru LN1
  unsigned short* wqkvT = (unsigned short*)(ws + 16 * MB);   // 6MB  [3072][1024]
  unsigned short* woT   = (unsigned short*)(ws + 22 * MB);   // 2MB
  unsigned short* w1T   = (unsigned short*)(ws + 24 * MB);   // 8MB
  unsigned short* w2T   = (unsigned short*)(ws + 32 * MB);   // 8MB
  unsigned short* Qb    = (unsigned short*)(ws + 40 * MB);   // 16MB
  unsigned short* Kb    = (unsigned short*)(ws + 56 * MB);   // 16MB
  unsigned short* Vtg   = (unsigned short*)(ws + 72 * MB);   // 32MB [(b,h,d)][s]
  unsigned short* aO    = (unsigned short*)(ws + 104 * MB);  // 16MB
  unsigned short* prjb  = (unsigned short*)(ws + 120 * MB);  // 16MB bf16 partial
  unsigned short* prj2b = (unsigned short*)(ws + 40 * MB);   // 16MB alias Qb (dead post-attn)
  unsigned short* hb    = (unsigned short*)(ws + 136 * MB);  // 16MB (old h region); LIVE thru LN2
  unsigned short* ffm   = (unsigned short*)(ws + 40 * MB);   // 64MB alias Qb..Vtg (post-LN1)
  unsigned short* ffob  = (unsigned short*)(ws + 104 * MB);  // 16MB alias aO (dead)
  unsigned short* ffo2b = (unsigned short*)(ws + 120 * MB);  // 16MB alias prjb (dead post-LN1)
  (void)ws_size; (void)in_sizes; (void)n_in; (void)out_size;

  // prep: cast x; weight transposes (B^T bf16); Wq/Wk/Wv stacked -> wqkvT
  cast_bf16<<<TOK * DM / 4 / 256, 256, 0, stream>>>(x, xb, TOK * DM / 4);
  transpose_cast4<<<dim3(DM / 32, DM / 32, 4), dim3(32, 8), 0, stream>>>(
      Wq, Wk, Wv, Wo, wqkvT, wqkvT + 1024 * 1024, wqkvT + 2048 * 1024, woT);
  transpose_cast<<<dim3(DFF / 32, DM / 32), dim3(32, 8), 0, stream>>>(W1, w1T, DM, DFF);
  transpose_cast<<<dim3(DM / 32, DFF / 32), dim3(32, 8), 0, stream>>>(W2, w2T, DFF, DM);

  // fused QKV projection (Q scaled for exp2-domain softmax; V transposed)
  gemm_qkv256<<<dim3(3 * DM / 256, TOK / 256), 512, 0, stream>>>(
      xb, wqkvT, bq, bk, bvv, Qb, Kb, Vtg);

  // attention (BQ=128)
  attn_kernel<<<dim3(SEQ / 128, BATCH * NH), 256, 0, stream>>>(Qb, Kb, Vtg, aO);

  // output projection, split-K x2 -> bf16 partials
  gemm256<<<dim3(DM / 256, TOK / 256, 2), 512, 0, stream>>>(
      aO, DM, woT, DM, DM / 2, bo, prjb, prj2b, DM, 1.0f, 0, 0);
  // LN1: hb = bf16(LN(xb + prjb + prj2b))  — base read from bf16 xb (-16MB)
  ln_res<<<TOK, 256, 0, stream>>>(nullptr, xb, prjb, prj2b, g1, be1, nullptr, hb);

  // FF1: relu(hb @ W1 + b1) -> bf16 ffm
  gemm256<<<dim3(DFF / 256, TOK / 256, 1), 512, 0, stream>>>(
      hb, DM, w1T, DM, DM, b1, ffm, nullptr, DFF, 1.0f, 1, 0);
  // FF2 split-K -> bf16 partials (z=0 + bias -> ffob; z=1 -> ffo2b)
  gemm256<<<dim3(DM / 256, TOK / 256, 2), 512, 0, stream>>>(
      ffm, DFF, w2T, DFF, DFF / 2, b2, ffob, ffo2b, DM, 1.0f, 0, 0);

  // LN2 -> d_out (fp32): LN(hb + ffob + ffo2b)
  ln_res<<<TOK, 256, 0, stream>>>(nullptr, hb, ffob, ffo2b, g2, be2,
                                  (float*)d_out, nullptr);
}